// Round 1
// baseline (1140.586 us; speedup 1.0000x reference)
//
#include <hip/hip_runtime.h>

#define N_NODES 100000
#define E_EDGES 1600000
#define IN_C    128
#define HID_C   64
#define OUT_C   64

// ---------------- degree ----------------
__global__ void deg_kernel(const int* __restrict__ edge_index, float* __restrict__ deg) {
    int e = blockIdx.x * blockDim.x + threadIdx.x;
    if (e < E_EDGES) {
        int dst = edge_index[e];          // row 0 = dst
        atomicAdd(&deg[dst], 1.0f);
    }
}

// ---------------- h0 = x @ W_init ----------------
__global__ __launch_bounds__(256) void init_gemm(const float* __restrict__ x,
                                                 const float* __restrict__ W,
                                                 float* __restrict__ h) {
    __shared__ float sW[IN_C * HID_C];    // 32 KB
    __shared__ float sx[4][IN_C];         // 2 KB
    int tid = threadIdx.x;
    for (int i = tid; i < IN_C * HID_C; i += 256) sW[i] = W[i];
    int row0 = blockIdx.x * 4;
    for (int i = tid; i < 4 * IN_C; i += 256) {
        int r = i >> 7, k = i & 127;
        int row = row0 + r;
        sx[r][k] = (row < N_NODES) ? x[row * IN_C + k] : 0.f;
    }
    __syncthreads();
    int r = tid >> 6, col = tid & 63;
    int row = row0 + r;
    if (row >= N_NODES) return;
    float acc = 0.f;
    #pragma unroll 8
    for (int k = 0; k < IN_C; ++k)
        acc = fmaf(sx[r][k], sW[k * HID_C + col], acc);
    h[row * HID_C + col] = acc;
}

// ---------------- scatter: agg[dst] += h[src] ----------------
__global__ __launch_bounds__(256) void scatter_kernel(const int* __restrict__ edge_index,
                                                      const float* __restrict__ h,
                                                      float* __restrict__ agg) {
    int gid = blockIdx.x * blockDim.x + threadIdx.x;
    int e = gid >> 6;
    int c = gid & 63;
    if (e >= E_EDGES) return;
    int dst = edge_index[e];
    int src = edge_index[E_EDGES + e];
    atomicAdd(&agg[dst * HID_C + c], h[src * HID_C + c]);
}

// ---------------- h_new = relu(agg/deg @ Wa + h @ Ws + b), in-place over agg ----------------
__global__ __launch_bounds__(256) void combine_kernel(float* __restrict__ agg,     // in: agg, out: h_new
                                                      const float* __restrict__ h,
                                                      const float* __restrict__ Wa,
                                                      const float* __restrict__ Ws,
                                                      const float* __restrict__ b,
                                                      const float* __restrict__ deg) {
    __shared__ float sWa[HID_C * HID_C];  // 16 KB
    __shared__ float sWs[HID_C * HID_C];  // 16 KB
    __shared__ float sA[4][HID_C];
    __shared__ float sH[4][HID_C];
    int tid = threadIdx.x;
    for (int i = tid; i < HID_C * HID_C; i += 256) { sWa[i] = Wa[i]; sWs[i] = Ws[i]; }
    int row0 = blockIdx.x * 4;
    for (int i = tid; i < 4 * HID_C; i += 256) {
        int r = i >> 6, k = i & 63;
        int row = row0 + r;
        float a = 0.f, hh = 0.f;
        if (row < N_NODES) { a = agg[row * HID_C + k]; hh = h[row * HID_C + k]; }
        sA[r][k] = a; sH[r][k] = hh;
    }
    __syncthreads();
    int r = tid >> 6, col = tid & 63;
    int row = row0 + r;
    if (row >= N_NODES) return;
    float inv = 1.0f / fmaxf(deg[row], 1.0f);
    float acc = b[col];
    #pragma unroll 8
    for (int k = 0; k < HID_C; ++k)
        acc = fmaf(sA[r][k] * inv, sWa[k * HID_C + col], fmaf(sH[r][k], sWs[k * HID_C + col], acc));
    agg[row * HID_C + col] = fmaxf(acc, 0.f);
}

// ---------------- out = h @ W_out ----------------
__global__ __launch_bounds__(256) void out_gemm(const float* __restrict__ h,
                                                const float* __restrict__ W,
                                                float* __restrict__ out) {
    __shared__ float sW[HID_C * OUT_C];   // 16 KB
    __shared__ float sH[4][HID_C];
    int tid = threadIdx.x;
    for (int i = tid; i < HID_C * OUT_C; i += 256) sW[i] = W[i];
    int row0 = blockIdx.x * 4;
    for (int i = tid; i < 4 * HID_C; i += 256) {
        int r = i >> 6, k = i & 63;
        int row = row0 + r;
        sH[r][k] = (row < N_NODES) ? h[row * HID_C + k] : 0.f;
    }
    __syncthreads();
    int r = tid >> 6, col = tid & 63;
    int row = row0 + r;
    if (row >= N_NODES) return;
    float acc = 0.f;
    #pragma unroll 8
    for (int k = 0; k < HID_C; ++k)
        acc = fmaf(sH[r][k], sW[k * OUT_C + col], acc);
    out[row * OUT_C + col] = acc;
}

extern "C" void kernel_launch(void* const* d_in, const int* in_sizes, int n_in,
                              void* d_out, int out_size, void* d_ws, size_t ws_size,
                              hipStream_t stream) {
    const float* x      = (const float*)d_in[0];
    const int*   ei     = (const int*)  d_in[1];
    const float* W_init = (const float*)d_in[2];
    const float* W_self = (const float*)d_in[3];
    const float* W_agg  = (const float*)d_in[4];
    const float* b      = (const float*)d_in[5];
    const float* W_out  = (const float*)d_in[6];
    float* out = (float*)d_out;

    char* ws = (char*)d_ws;
    const size_t MB = 1 << 20;
    float* deg = (float*)(ws + 0);            // 400 KB used
    float* hA  = (float*)(ws + 1 * MB);       // 25.6 MB
    float* hB  = (float*)(ws + 27 * MB);      // 25.6 MB

    const size_t HBYTES = (size_t)N_NODES * HID_C * sizeof(float);

    // degree
    hipMemsetAsync(deg, 0, N_NODES * sizeof(float), stream);
    deg_kernel<<<(E_EDGES + 255) / 256, 256, 0, stream>>>(ei, deg);

    // h0 = x @ W_init  -> hA
    init_gemm<<<(N_NODES + 3) / 4, 256, 0, stream>>>(x, W_init, hA);

    const int sc_grid = (E_EDGES * HID_C) / 256;          // 400000
    const int cb_grid = (N_NODES + 3) / 4;                // 25000

    // layer 0: h in hA, agg in hB, combine writes hB
    hipMemsetAsync(hB, 0, HBYTES, stream);
    scatter_kernel<<<sc_grid, 256, 0, stream>>>(ei, hA, hB);
    combine_kernel<<<cb_grid, 256, 0, stream>>>(hB, hA, W_agg + 0 * HID_C * HID_C,
                                                W_self + 0 * HID_C * HID_C, b + 0 * HID_C, deg);

    // layer 1: h in hB, agg in hA, combine writes hA
    hipMemsetAsync(hA, 0, HBYTES, stream);
    scatter_kernel<<<sc_grid, 256, 0, stream>>>(ei, hB, hA);
    combine_kernel<<<cb_grid, 256, 0, stream>>>(hA, hB, W_agg + 1 * HID_C * HID_C,
                                                W_self + 1 * HID_C * HID_C, b + 1 * HID_C, deg);

    // out = h2 @ W_out
    out_gemm<<<cb_grid, 256, 0, stream>>>(hA, W_out, out);
}

// Round 2
// 1029.789 us; speedup vs baseline: 1.1076x; 1.1076x over previous
//
#include <hip/hip_runtime.h>

#define N_NODES 100000
#define E_EDGES 1600000
#define IN_C    128
#define HID_C   64
#define OUT_C   64
#define ROWS    32          // nodes per block in fused/GEMM kernels

// ---------------- histogram: cnt[dst]++ ----------------
__global__ void hist_kernel(const int* __restrict__ edge_index, int* __restrict__ cnt) {
    int e = blockIdx.x * blockDim.x + threadIdx.x;
    if (e < E_EDGES) atomicAdd(&cnt[edge_index[e]], 1);
}

// ---------------- block-level inclusive scan ----------------
__global__ __launch_bounds__(1024) void scan_block(const int* __restrict__ cnt,
                                                   int* __restrict__ iscan,
                                                   int* __restrict__ bsum) {
    __shared__ int s[1024];
    int i = blockIdx.x * 1024 + threadIdx.x;
    int v = (i < N_NODES) ? cnt[i] : 0;
    s[threadIdx.x] = v;
    __syncthreads();
    for (int off = 1; off < 1024; off <<= 1) {
        int t = (threadIdx.x >= off) ? s[threadIdx.x - off] : 0;
        __syncthreads();
        s[threadIdx.x] += t;
        __syncthreads();
    }
    if (i < N_NODES) iscan[i] = s[threadIdx.x];
    if (threadIdx.x == 1023) bsum[blockIdx.x] = s[1023];
}

// ---------------- scan of block partials (single block), in-place -> exclusive ----------------
__global__ __launch_bounds__(128) void scan_partials(int* __restrict__ bsum, int nb) {
    __shared__ int s[128];
    int v = (threadIdx.x < nb) ? bsum[threadIdx.x] : 0;
    s[threadIdx.x] = v;
    __syncthreads();
    for (int off = 1; off < 128; off <<= 1) {
        int t = (threadIdx.x >= off) ? s[threadIdx.x - off] : 0;
        __syncthreads();
        s[threadIdx.x] += t;
        __syncthreads();
    }
    if (threadIdx.x < nb) bsum[threadIdx.x] = s[threadIdx.x] - v;   // exclusive
}

// ---------------- row_start[i] = boff[blk] + iscan[i] - cnt[i] ----------------
__global__ __launch_bounds__(1024) void finalize_rs(const int* __restrict__ cnt,
                                                    const int* __restrict__ iscan,
                                                    const int* __restrict__ bsum,
                                                    int* __restrict__ rs) {
    int i = blockIdx.x * 1024 + threadIdx.x;
    if (i < N_NODES) rs[i] = bsum[blockIdx.x] + iscan[i] - cnt[i];
}

// ---------------- fill CSR: csr[rs[dst] + pos] = src ----------------
__global__ void fill_csr(const int* __restrict__ edge_index,
                         const int* __restrict__ rs,
                         int* __restrict__ cursor,
                         int* __restrict__ csr) {
    int e = blockIdx.x * blockDim.x + threadIdx.x;
    if (e < E_EDGES) {
        int dst = edge_index[e];
        int src = edge_index[E_EDGES + e];
        int p = atomicAdd(&cursor[dst], 1);
        csr[rs[dst] + p] = src;
    }
}

// ---------------- h0 = x @ W_init, 32 rows/block ----------------
__global__ __launch_bounds__(256) void init_gemm(const float* __restrict__ x,
                                                 const float* __restrict__ W,
                                                 float* __restrict__ h) {
    __shared__ float sW[IN_C * HID_C];    // 32 KB
    __shared__ float sx[ROWS][IN_C];      // 16 KB
    int tid = threadIdx.x;
    for (int i = tid; i < IN_C * HID_C; i += 256) sW[i] = W[i];
    int row0 = blockIdx.x * ROWS;
    for (int i = tid; i < ROWS * IN_C; i += 256) {
        int r = i >> 7, k = i & 127;
        sx[r][k] = x[(row0 + r) * IN_C + k];
    }
    __syncthreads();
    int col = tid & 63, rg = tid >> 6;    // rg in [0,4): rows rg*8..rg*8+7
    float o[8];
    #pragma unroll
    for (int j = 0; j < 8; ++j) o[j] = 0.f;
    for (int k = 0; k < IN_C; ++k) {
        float wv = sW[k * HID_C + col];
        #pragma unroll
        for (int j = 0; j < 8; ++j)
            o[j] = fmaf(sx[rg * 8 + j][k], wv, o[j]);
    }
    #pragma unroll
    for (int j = 0; j < 8; ++j)
        h[(row0 + rg * 8 + j) * HID_C + col] = o[j];
}

// ---------------- fused: gather-mean + combine GEMM + ReLU ----------------
__global__ __launch_bounds__(256) void fused_layer(const float* __restrict__ h,
                                                   const int* __restrict__ rs,
                                                   const int* __restrict__ cnt,
                                                   const int* __restrict__ csr,
                                                   const float* __restrict__ Wa,
                                                   const float* __restrict__ Ws,
                                                   const float* __restrict__ b,
                                                   float* __restrict__ hout) {
    __shared__ float sWa[HID_C * HID_C];  // 16 KB
    __shared__ float sWs[HID_C * HID_C];  // 16 KB
    __shared__ float sA[ROWS][HID_C];     // 8 KB
    __shared__ float sH[ROWS][HID_C];     // 8 KB
    int tid = threadIdx.x;
    for (int i = tid; i < HID_C * HID_C; i += 256) { sWa[i] = Wa[i]; sWs[i] = Ws[i]; }
    int row0 = blockIdx.x * ROWS;
    int wave = tid >> 6, lane = tid & 63;
    // gather phase: each wave handles 8 nodes
    for (int i = 0; i < ROWS / 4; ++i) {
        int rl = wave * (ROWS / 4) + i;
        int row = row0 + rl;
        int start = rs[row];
        int d = cnt[row];
        float acc = 0.f;
        for (int j = 0; j < d; ++j) {
            int src = csr[start + j];
            acc += h[src * HID_C + lane];
        }
        sH[rl][lane] = h[row * HID_C + lane];
        sA[rl][lane] = acc * (1.f / fmaxf((float)d, 1.f));
    }
    __syncthreads();
    // GEMM phase: h_new = relu(agg@Wa + h@Ws + b)
    int col = lane, rg = wave;
    float bias = b[col];
    float o[8];
    #pragma unroll
    for (int j = 0; j < 8; ++j) o[j] = bias;
    for (int k = 0; k < HID_C; ++k) {
        float wA = sWa[k * HID_C + col];
        float wS = sWs[k * HID_C + col];
        #pragma unroll
        for (int j = 0; j < 8; ++j) {
            int r = rg * 8 + j;
            o[j] = fmaf(sA[r][k], wA, fmaf(sH[r][k], wS, o[j]));
        }
    }
    #pragma unroll
    for (int j = 0; j < 8; ++j)
        hout[(row0 + rg * 8 + j) * HID_C + col] = fmaxf(o[j], 0.f);
}

// ---------------- out = h @ W_out, 32 rows/block ----------------
__global__ __launch_bounds__(256) void out_gemm(const float* __restrict__ h,
                                               const float* __restrict__ W,
                                               float* __restrict__ out) {
    __shared__ float sW[HID_C * OUT_C];   // 16 KB
    __shared__ float sH[ROWS][HID_C];     // 8 KB
    int tid = threadIdx.x;
    for (int i = tid; i < HID_C * OUT_C; i += 256) sW[i] = W[i];
    int row0 = blockIdx.x * ROWS;
    for (int i = tid; i < ROWS * HID_C; i += 256) {
        int r = i >> 6, k = i & 63;
        sH[r][k] = h[(row0 + r) * HID_C + k];
    }
    __syncthreads();
    int col = tid & 63, rg = tid >> 6;
    float o[8];
    #pragma unroll
    for (int j = 0; j < 8; ++j) o[j] = 0.f;
    for (int k = 0; k < HID_C; ++k) {
        float wv = sW[k * OUT_C + col];
        #pragma unroll
        for (int j = 0; j < 8; ++j)
            o[j] = fmaf(sH[rg * 8 + j][k], wv, o[j]);
    }
    #pragma unroll
    for (int j = 0; j < 8; ++j)
        out[(row0 + rg * 8 + j) * OUT_C + col] = o[j];
}

extern "C" void kernel_launch(void* const* d_in, const int* in_sizes, int n_in,
                              void* d_out, int out_size, void* d_ws, size_t ws_size,
                              hipStream_t stream) {
    const float* x      = (const float*)d_in[0];
    const int*   ei     = (const int*)  d_in[1];
    const float* W_init = (const float*)d_in[2];
    const float* W_self = (const float*)d_in[3];
    const float* W_agg  = (const float*)d_in[4];
    const float* b      = (const float*)d_in[5];
    const float* W_out  = (const float*)d_in[6];
    float* out = (float*)d_out;

    char* ws = (char*)d_ws;
    const size_t KB = 1 << 10;
    int*   cnt    = (int*)(ws + 0);            // 400 KB
    int*   rs     = (int*)(ws + 512 * KB);     // 400 KB
    int*   cursor = (int*)(ws + 1024 * KB);    // 400 KB
    int*   iscan  = (int*)(ws + 1536 * KB);    // 400 KB
    int*   bsum   = (int*)(ws + 2048 * KB);    // 512 B
    int*   csr    = (int*)(ws + 3072 * KB);    // 6.4 MB
    float* hA     = (float*)(ws + 10240 * KB); // 25.6 MB
    float* hB     = (float*)d_out;             // reuse output buffer as ping-pong

    const int SCAN_BLOCKS = (N_NODES + 1023) / 1024;   // 98

    // CSR build
    hipMemsetAsync(cnt, 0, N_NODES * sizeof(int), stream);
    hipMemsetAsync(cursor, 0, N_NODES * sizeof(int), stream);
    hist_kernel<<<(E_EDGES + 255) / 256, 256, 0, stream>>>(ei, cnt);
    scan_block<<<SCAN_BLOCKS, 1024, 0, stream>>>(cnt, iscan, bsum);
    scan_partials<<<1, 128, 0, stream>>>(bsum, SCAN_BLOCKS);
    finalize_rs<<<SCAN_BLOCKS, 1024, 0, stream>>>(cnt, iscan, bsum, rs);
    fill_csr<<<(E_EDGES + 255) / 256, 256, 0, stream>>>(ei, rs, cursor, csr);

    const int GB = N_NODES / ROWS;   // 3125 (exact)

    // h0 = x @ W_init -> hA
    init_gemm<<<GB, 256, 0, stream>>>(x, W_init, hA);

    // layer 0: hA -> hB (d_out as scratch)
    fused_layer<<<GB, 256, 0, stream>>>(hA, rs, cnt, csr,
                                        W_agg + 0 * HID_C * HID_C,
                                        W_self + 0 * HID_C * HID_C,
                                        b + 0 * HID_C, hB);
    // layer 1: hB -> hA
    fused_layer<<<GB, 256, 0, stream>>>(hB, rs, cnt, csr,
                                        W_agg + 1 * HID_C * HID_C,
                                        W_self + 1 * HID_C * HID_C,
                                        b + 1 * HID_C, hA);
    // out = h2 @ W_out
    out_gemm<<<GB, 256, 0, stream>>>(hA, W_out, out);
}

// Round 3
// 494.541 us; speedup vs baseline: 2.3064x; 2.0823x over previous
//
#include <hip/hip_runtime.h>

#define N_NODES 100000
#define E_EDGES 1600000
#define IN_C    128
#define HID_C   64
#define OUT_C   64
#define ROWS    32          // nodes per block in fused/GEMM kernels

// ---------------- histogram: cnt[dst]++ ----------------
__global__ void hist_kernel(const int* __restrict__ edge_index, int* __restrict__ cnt) {
    int e = blockIdx.x * blockDim.x + threadIdx.x;
    if (e < E_EDGES) atomicAdd(&cnt[edge_index[e]], 1);
}

// ---------------- block-level inclusive scan ----------------
__global__ __launch_bounds__(1024) void scan_block(const int* __restrict__ cnt,
                                                   int* __restrict__ iscan,
                                                   int* __restrict__ bsum) {
    __shared__ int s[1024];
    int i = blockIdx.x * 1024 + threadIdx.x;
    int v = (i < N_NODES) ? cnt[i] : 0;
    s[threadIdx.x] = v;
    __syncthreads();
    for (int off = 1; off < 1024; off <<= 1) {
        int t = (threadIdx.x >= off) ? s[threadIdx.x - off] : 0;
        __syncthreads();
        s[threadIdx.x] += t;
        __syncthreads();
    }
    if (i < N_NODES) iscan[i] = s[threadIdx.x];
    if (threadIdx.x == 1023) bsum[blockIdx.x] = s[1023];
}

// ---------------- scan of block partials (single block), in-place -> exclusive ----------------
__global__ __launch_bounds__(128) void scan_partials(int* __restrict__ bsum, int nb) {
    __shared__ int s[128];
    int v = (threadIdx.x < nb) ? bsum[threadIdx.x] : 0;
    s[threadIdx.x] = v;
    __syncthreads();
    for (int off = 1; off < 128; off <<= 1) {
        int t = (threadIdx.x >= off) ? s[threadIdx.x - off] : 0;
        __syncthreads();
        s[threadIdx.x] += t;
        __syncthreads();
    }
    if (threadIdx.x < nb) bsum[threadIdx.x] = s[threadIdx.x] - v;   // exclusive
}

// ---------------- row_start[i] = boff[blk] + iscan[i] - cnt[i] ----------------
__global__ __launch_bounds__(1024) void finalize_rs(const int* __restrict__ cnt,
                                                    const int* __restrict__ iscan,
                                                    const int* __restrict__ bsum,
                                                    int* __restrict__ rs) {
    int i = blockIdx.x * 1024 + threadIdx.x;
    if (i < N_NODES) rs[i] = bsum[blockIdx.x] + iscan[i] - cnt[i];
}

// ---------------- fill CSR: csr[rs[dst] + pos] = src ----------------
__global__ void fill_csr(const int* __restrict__ edge_index,
                         const int* __restrict__ rs,
                         int* __restrict__ cursor,
                         int* __restrict__ csr) {
    int e = blockIdx.x * blockDim.x + threadIdx.x;
    if (e < E_EDGES) {
        int dst = edge_index[e];
        int src = edge_index[E_EDGES + e];
        int p = atomicAdd(&cursor[dst], 1);
        csr[rs[dst] + p] = src;
    }
}

// ---------------- h0 = x @ W_init, 32 rows/block ----------------
__global__ __launch_bounds__(256) void init_gemm(const float* __restrict__ x,
                                                 const float* __restrict__ W,
                                                 float* __restrict__ h) {
    __shared__ float sW[IN_C * HID_C];    // 32 KB
    __shared__ float sx[ROWS][IN_C];      // 16 KB
    int tid = threadIdx.x;
    const float4* W4 = (const float4*)W;
    float4* sW4 = (float4*)sW;
    for (int i = tid; i < (IN_C * HID_C) / 4; i += 256) sW4[i] = W4[i];
    int row0 = blockIdx.x * ROWS;
    const float4* x4 = (const float4*)x;
    for (int i = tid; i < (ROWS * IN_C) / 4; i += 256) {
        int r = i >> 5, q = i & 31;    // 32 float4 per row
        *(float4*)&sx[r][q * 4] = x4[(size_t)(row0 + r) * (IN_C / 4) + q];
    }
    __syncthreads();
    int col = tid & 63, rg = tid >> 6;    // rg in [0,4): rows rg*8..rg*8+7
    float o[8];
    #pragma unroll
    for (int j = 0; j < 8; ++j) o[j] = 0.f;
    for (int k = 0; k < IN_C; ++k) {
        float wv = sW[k * HID_C + col];
        #pragma unroll
        for (int j = 0; j < 8; ++j)
            o[j] = fmaf(sx[rg * 8 + j][k], wv, o[j]);
    }
    #pragma unroll
    for (int j = 0; j < 8; ++j)
        h[(size_t)(row0 + rg * 8 + j) * HID_C + col] = o[j];
}

// ---------------- fused: gather-mean + combine GEMM + ReLU ----------------
__global__ __launch_bounds__(256) void fused_layer(const float* __restrict__ h,
                                                   const int* __restrict__ rs,
                                                   const int* __restrict__ cnt,
                                                   const int* __restrict__ csr,
                                                   const float* __restrict__ Wa,
                                                   const float* __restrict__ Ws,
                                                   const float* __restrict__ b,
                                                   float* __restrict__ hout) {
    __shared__ float sWa[HID_C * HID_C];  // 16 KB
    __shared__ float sWs[HID_C * HID_C];  // 16 KB
    __shared__ float sA[ROWS][HID_C];     // 8 KB
    __shared__ float sH[ROWS][HID_C];     // 8 KB
    int tid = threadIdx.x;
    {
        const float4* Wa4 = (const float4*)Wa;
        const float4* Ws4 = (const float4*)Ws;
        float4* sWa4 = (float4*)sWa;
        float4* sWs4 = (float4*)sWs;
        for (int i = tid; i < (HID_C * HID_C) / 4; i += 256) { sWa4[i] = Wa4[i]; sWs4[i] = Ws4[i]; }
    }
    int row0 = blockIdx.x * ROWS;
    int wave = tid >> 6, lane = tid & 63;
    // gather phase: each wave handles 8 consecutive nodes; 8-deep MLP on edges
    for (int i = 0; i < 8; ++i) {
        int rl = wave * 8 + i;
        int row = row0 + rl;
        int start = __builtin_amdgcn_readfirstlane(rs[row]);
        int d     = __builtin_amdgcn_readfirstlane(cnt[row]);
        float selfv = h[(size_t)row * HID_C + lane];   // in flight during gather
        float acc[8];
        #pragma unroll
        for (int u = 0; u < 8; ++u) acc[u] = 0.f;
        for (int j = 0; j < d; j += 8) {
            int srcs[8];
            #pragma unroll
            for (int u = 0; u < 8; ++u) {
                int jj = j + u;
                srcs[u] = csr[start + (jj < d ? jj : d - 1)];
            }
            #pragma unroll
            for (int u = 0; u < 8; ++u) {
                float v = h[(size_t)srcs[u] * HID_C + lane];
                acc[u] += (j + u < d) ? v : 0.f;
            }
        }
        float s = ((acc[0] + acc[1]) + (acc[2] + acc[3])) + ((acc[4] + acc[5]) + (acc[6] + acc[7]));
        sH[rl][lane] = selfv;
        sA[rl][lane] = s * (1.f / fmaxf((float)d, 1.f));
    }
    __syncthreads();
    // GEMM phase: h_new = relu(agg@Wa + h@Ws + b)
    int col = lane, rg = wave;
    float bias = b[col];
    float o[8];
    #pragma unroll
    for (int j = 0; j < 8; ++j) o[j] = bias;
    for (int k = 0; k < HID_C; ++k) {
        float wA = sWa[k * HID_C + col];
        float wS = sWs[k * HID_C + col];
        #pragma unroll
        for (int j = 0; j < 8; ++j) {
            int r = rg * 8 + j;
            o[j] = fmaf(sA[r][k], wA, fmaf(sH[r][k], wS, o[j]));
        }
    }
    #pragma unroll
    for (int j = 0; j < 8; ++j)
        hout[(size_t)(row0 + rg * 8 + j) * HID_C + col] = fmaxf(o[j], 0.f);
}

// ---------------- out = h @ W_out, 32 rows/block ----------------
__global__ __launch_bounds__(256) void out_gemm(const float* __restrict__ h,
                                               const float* __restrict__ W,
                                               float* __restrict__ out) {
    __shared__ float sW[HID_C * OUT_C];   // 16 KB
    __shared__ float sH[ROWS][HID_C];     // 8 KB
    int tid = threadIdx.x;
    const float4* W4 = (const float4*)W;
    float4* sW4 = (float4*)sW;
    for (int i = tid; i < (HID_C * OUT_C) / 4; i += 256) sW4[i] = W4[i];
    int row0 = blockIdx.x * ROWS;
    const float4* h4 = (const float4*)h;
    for (int i = tid; i < (ROWS * HID_C) / 4; i += 256) {
        int r = i >> 4, q = i & 15;    // 16 float4 per row
        *(float4*)&sH[r][q * 4] = h4[(size_t)(row0 + r) * (HID_C / 4) + q];
    }
    __syncthreads();
    int col = tid & 63, rg = tid >> 6;
    float o[8];
    #pragma unroll
    for (int j = 0; j < 8; ++j) o[j] = 0.f;
    for (int k = 0; k < HID_C; ++k) {
        float wv = sW[k * OUT_C + col];
        #pragma unroll
        for (int j = 0; j < 8; ++j)
            o[j] = fmaf(sH[rg * 8 + j][k], wv, o[j]);
    }
    #pragma unroll
    for (int j = 0; j < 8; ++j)
        out[(size_t)(row0 + rg * 8 + j) * OUT_C + col] = o[j];
}

extern "C" void kernel_launch(void* const* d_in, const int* in_sizes, int n_in,
                              void* d_out, int out_size, void* d_ws, size_t ws_size,
                              hipStream_t stream) {
    const float* x      = (const float*)d_in[0];
    const int*   ei     = (const int*)  d_in[1];
    const float* W_init = (const float*)d_in[2];
    const float* W_self = (const float*)d_in[3];
    const float* W_agg  = (const float*)d_in[4];
    const float* b      = (const float*)d_in[5];
    const float* W_out  = (const float*)d_in[6];
    float* out = (float*)d_out;

    char* ws = (char*)d_ws;
    const size_t KB = 1 << 10;
    int*   cnt    = (int*)(ws + 0);            // 400 KB
    int*   rs     = (int*)(ws + 512 * KB);     // 400 KB
    int*   cursor = (int*)(ws + 1024 * KB);    // 400 KB
    int*   iscan  = (int*)(ws + 1536 * KB);    // 400 KB
    int*   bsum   = (int*)(ws + 2048 * KB);    // 512 B
    int*   csr    = (int*)(ws + 3072 * KB);    // 6.4 MB
    float* hA     = (float*)(ws + 10240 * KB); // 25.6 MB
    float* hB     = (float*)d_out;             // reuse output buffer as ping-pong

    const int SCAN_BLOCKS = (N_NODES + 1023) / 1024;   // 98

    // CSR build
    hipMemsetAsync(cnt, 0, N_NODES * sizeof(int), stream);
    hipMemsetAsync(cursor, 0, N_NODES * sizeof(int), stream);
    hist_kernel<<<(E_EDGES + 255) / 256, 256, 0, stream>>>(ei, cnt);
    scan_block<<<SCAN_BLOCKS, 1024, 0, stream>>>(cnt, iscan, bsum);
    scan_partials<<<1, 128, 0, stream>>>(bsum, SCAN_BLOCKS);
    finalize_rs<<<SCAN_BLOCKS, 1024, 0, stream>>>(cnt, iscan, bsum, rs);
    fill_csr<<<(E_EDGES + 255) / 256, 256, 0, stream>>>(ei, rs, cursor, csr);

    const int GB = N_NODES / ROWS;   // 3125 (exact)

    // h0 = x @ W_init -> hA
    init_gemm<<<GB, 256, 0, stream>>>(x, W_init, hA);

    // layer 0: hA -> hB (d_out as scratch)
    fused_layer<<<GB, 256, 0, stream>>>(hA, rs, cnt, csr,
                                        W_agg + 0 * HID_C * HID_C,
                                        W_self + 0 * HID_C * HID_C,
                                        b + 0 * HID_C, hB);
    // layer 1: hB -> hA
    fused_layer<<<GB, 256, 0, stream>>>(hB, rs, cnt, csr,
                                        W_agg + 1 * HID_C * HID_C,
                                        W_self + 1 * HID_C * HID_C,
                                        b + 1 * HID_C, hA);
    // out = h2 @ W_out
    out_gemm<<<GB, 256, 0, stream>>>(hA, W_out, out);
}

// Round 4
// 427.730 us; speedup vs baseline: 2.6666x; 1.1562x over previous
//
#include <hip/hip_runtime.h>
#include <hip/hip_fp16.h>

#define N_NODES 100000
#define E_EDGES 1600000
#define IN_C    128
#define HID_C   64
#define OUT_C   64
#define ROWS    32          // nodes per block in fused/GEMM kernels

// ---------------- histogram: cnt[dst]++ ----------------
__global__ void hist_kernel(const int* __restrict__ edge_index, int* __restrict__ cnt) {
    int e = blockIdx.x * blockDim.x + threadIdx.x;
    if (e < E_EDGES) atomicAdd(&cnt[edge_index[e]], 1);
}

// ---------------- block-level inclusive scan ----------------
__global__ __launch_bounds__(1024) void scan_block(const int* __restrict__ cnt,
                                                   int* __restrict__ iscan,
                                                   int* __restrict__ bsum) {
    __shared__ int s[1024];
    int i = blockIdx.x * 1024 + threadIdx.x;
    int v = (i < N_NODES) ? cnt[i] : 0;
    s[threadIdx.x] = v;
    __syncthreads();
    for (int off = 1; off < 1024; off <<= 1) {
        int t = (threadIdx.x >= off) ? s[threadIdx.x - off] : 0;
        __syncthreads();
        s[threadIdx.x] += t;
        __syncthreads();
    }
    if (i < N_NODES) iscan[i] = s[threadIdx.x];
    if (threadIdx.x == 1023) bsum[blockIdx.x] = s[1023];
}

// ---------------- scan of block partials (single block), in-place -> exclusive ----------------
__global__ __launch_bounds__(128) void scan_partials(int* __restrict__ bsum, int nb) {
    __shared__ int s[128];
    int v = (threadIdx.x < nb) ? bsum[threadIdx.x] : 0;
    s[threadIdx.x] = v;
    __syncthreads();
    for (int off = 1; off < 128; off <<= 1) {
        int t = (threadIdx.x >= off) ? s[threadIdx.x - off] : 0;
        __syncthreads();
        s[threadIdx.x] += t;
        __syncthreads();
    }
    if (threadIdx.x < nb) bsum[threadIdx.x] = s[threadIdx.x] - v;   // exclusive
}

// ---------------- row_start[i] = boff[blk] + iscan[i] - cnt[i] ----------------
__global__ __launch_bounds__(1024) void finalize_rs(const int* __restrict__ cnt,
                                                    const int* __restrict__ iscan,
                                                    const int* __restrict__ bsum,
                                                    int* __restrict__ rs) {
    int i = blockIdx.x * 1024 + threadIdx.x;
    if (i < N_NODES) rs[i] = bsum[blockIdx.x] + iscan[i] - cnt[i];
}

// ---------------- fill CSR: csr[rs[dst] + pos] = src ----------------
__global__ void fill_csr(const int* __restrict__ edge_index,
                         const int* __restrict__ rs,
                         int* __restrict__ cursor,
                         int* __restrict__ csr) {
    int e = blockIdx.x * blockDim.x + threadIdx.x;
    if (e < E_EDGES) {
        int dst = edge_index[e];
        int src = edge_index[E_EDGES + e];
        int p = atomicAdd(&cursor[dst], 1);
        csr[rs[dst] + p] = src;
    }
}

// ---------------- h0 = x @ W_init, fp16 out, 32 rows/block ----------------
__global__ __launch_bounds__(256) void init_gemm(const float* __restrict__ x,
                                                 const float* __restrict__ W,
                                                 __half* __restrict__ h) {
    __shared__ __half sW[IN_C * HID_C];   // 16 KB, [(k>>1)*128 + col*2 + (k&1)]
    __shared__ float sx[ROWS][IN_C];      // 16 KB
    int tid = threadIdx.x;
    for (int i = tid; i < IN_C * HID_C; i += 256) {
        int k = i >> 6, col = i & 63;
        sW[(k >> 1) * 128 + col * 2 + (k & 1)] = __float2half(W[i]);
    }
    int row0 = blockIdx.x * ROWS;
    const float4* x4 = (const float4*)x;
    for (int i = tid; i < (ROWS * IN_C) / 4; i += 256) {
        int r = i >> 5, q = i & 31;    // 32 float4 per row
        *(float4*)&sx[r][q * 4] = x4[(size_t)(row0 + r) * (IN_C / 4) + q];
    }
    __syncthreads();
    int col = tid & 63, rg = tid >> 6;    // rg in [0,4): rows rg*8..rg*8+7
    float o[8];
    #pragma unroll
    for (int j = 0; j < 8; ++j) o[j] = 0.f;
    const __half2* sW2 = (const __half2*)sW;
    for (int k2 = 0; k2 < IN_C / 2; ++k2) {
        float2 wv = __half22float2(sW2[k2 * 64 + col]);
        #pragma unroll
        for (int j = 0; j < 8; ++j) {
            o[j] = fmaf(sx[rg * 8 + j][2 * k2], wv.x, o[j]);
            o[j] = fmaf(sx[rg * 8 + j][2 * k2 + 1], wv.y, o[j]);
        }
    }
    #pragma unroll
    for (int j = 0; j < 8; ++j)
        h[(size_t)(row0 + rg * 8 + j) * HID_C + col] = __float2half(o[j]);
}

// ---------------- fused: gather-mean (fp16 h) + combine GEMM + ReLU ----------------
__global__ __launch_bounds__(256) void fused_layer(const __half* __restrict__ h,
                                                   const int* __restrict__ rs,
                                                   const int* __restrict__ cnt,
                                                   const int* __restrict__ csr,
                                                   const float* __restrict__ Wa,
                                                   const float* __restrict__ Ws,
                                                   const float* __restrict__ b,
                                                   __half* __restrict__ hout) {
    __shared__ __half sWa[HID_C * HID_C];  // 8 KB
    __shared__ __half sWs[HID_C * HID_C];  // 8 KB
    __shared__ float sA[ROWS][HID_C];      // 8 KB
    __shared__ float sH[ROWS][HID_C];      // 8 KB
    int tid = threadIdx.x;
    for (int i = tid; i < HID_C * HID_C; i += 256) {
        int k = i >> 6, col = i & 63;
        int li = (k >> 1) * 128 + col * 2 + (k & 1);
        sWa[li] = __float2half(Wa[i]);
        sWs[li] = __float2half(Ws[i]);
    }
    int row0 = blockIdx.x * ROWS;
    int wave = tid >> 6, lane = tid & 63;
    int par = lane >> 5;          // lanes 0-31: even edge; 32-63: odd edge
    int c   = lane & 31;          // half2 channel index (channels 2c, 2c+1)
    const __half2* hp = (const __half2*)h;
    // gather phase: each wave handles 8 consecutive nodes; 16 edges in flight
    for (int i = 0; i < 8; ++i) {
        int rl = wave * 8 + i;
        int row = row0 + rl;
        int start = __builtin_amdgcn_readfirstlane(rs[row]);
        int d     = __builtin_amdgcn_readfirstlane(cnt[row]);
        __half2 sv = hp[(size_t)row * 32 + c];
        float2 acc[8];
        #pragma unroll
        for (int u = 0; u < 8; ++u) { acc[u].x = 0.f; acc[u].y = 0.f; }
        for (int j = 0; j < d; j += 16) {
            int idx[8];
            #pragma unroll
            for (int u = 0; u < 8; ++u) {
                int e = j + 2 * u + par;
                bool v = e < d;
                int sv_ = csr[start + (v ? e : 0)];
                idx[u] = v ? sv_ : -1;
            }
            #pragma unroll
            for (int u = 0; u < 8; ++u) {
                bool v = idx[u] >= 0;
                int src = v ? idx[u] : 0;
                float2 f = __half22float2(hp[(size_t)src * 32 + c]);
                acc[u].x += v ? f.x : 0.f;
                acc[u].y += v ? f.y : 0.f;
            }
        }
        float ax = ((acc[0].x + acc[1].x) + (acc[2].x + acc[3].x)) +
                   ((acc[4].x + acc[5].x) + (acc[6].x + acc[7].x));
        float ay = ((acc[0].y + acc[1].y) + (acc[2].y + acc[3].y)) +
                   ((acc[4].y + acc[5].y) + (acc[6].y + acc[7].y));
        ax += __shfl_xor(ax, 32);
        ay += __shfl_xor(ay, 32);
        float inv = 1.f / fmaxf((float)d, 1.f);
        float2 svf = __half22float2(sv);
        if (lane < 32) {
            float2 a2; a2.x = ax * inv; a2.y = ay * inv;
            *(float2*)&sA[rl][2 * c] = a2;
            *(float2*)&sH[rl][2 * c] = svf;
        }
    }
    __syncthreads();
    // GEMM phase: h_new = relu(agg@Wa + h@Ws + b)
    int col = lane, rg = wave;
    float bias = b[col];
    float o[8];
    #pragma unroll
    for (int j = 0; j < 8; ++j) o[j] = bias;
    const __half2* wa2 = (const __half2*)sWa;
    const __half2* ws2 = (const __half2*)sWs;
    for (int k2 = 0; k2 < HID_C / 2; ++k2) {
        float2 wA = __half22float2(wa2[k2 * 64 + col]);
        float2 wS = __half22float2(ws2[k2 * 64 + col]);
        #pragma unroll
        for (int j = 0; j < 8; ++j) {
            int r = rg * 8 + j;
            o[j] = fmaf(sA[r][2 * k2],     wA.x, o[j]);
            o[j] = fmaf(sA[r][2 * k2 + 1], wA.y, o[j]);
            o[j] = fmaf(sH[r][2 * k2],     wS.x, o[j]);
            o[j] = fmaf(sH[r][2 * k2 + 1], wS.y, o[j]);
        }
    }
    #pragma unroll
    for (int j = 0; j < 8; ++j)
        hout[(size_t)(row0 + rg * 8 + j) * HID_C + col] = __float2half(fmaxf(o[j], 0.f));
}

// ---------------- out = h @ W_out (fp16 h in, fp32 out), 32 rows/block ----------------
__global__ __launch_bounds__(256) void out_gemm(const __half* __restrict__ h,
                                                const float* __restrict__ W,
                                                float* __restrict__ out) {
    __shared__ __half sW[HID_C * OUT_C];  // 8 KB
    __shared__ float sH[ROWS][HID_C];     // 8 KB
    int tid = threadIdx.x;
    for (int i = tid; i < HID_C * OUT_C; i += 256) {
        int k = i >> 6, col = i & 63;
        sW[(k >> 1) * 128 + col * 2 + (k & 1)] = __float2half(W[i]);
    }
    int row0 = blockIdx.x * ROWS;
    const __half2* h2 = (const __half2*)h;
    for (int i = tid; i < (ROWS * HID_C) / 2; i += 256) {
        int r = i >> 5, q = i & 31;    // 32 half2 per row
        float2 f = __half22float2(h2[(size_t)(row0 + r) * 32 + q]);
        *(float2*)&sH[r][q * 2] = f;
    }
    __syncthreads();
    int col = tid & 63, rg = tid >> 6;
    float o[8];
    #pragma unroll
    for (int j = 0; j < 8; ++j) o[j] = 0.f;
    const __half2* sW2 = (const __half2*)sW;
    for (int k2 = 0; k2 < HID_C / 2; ++k2) {
        float2 wv = __half22float2(sW2[k2 * 64 + col]);
        #pragma unroll
        for (int j = 0; j < 8; ++j) {
            o[j] = fmaf(sH[rg * 8 + j][2 * k2],     wv.x, o[j]);
            o[j] = fmaf(sH[rg * 8 + j][2 * k2 + 1], wv.y, o[j]);
        }
    }
    #pragma unroll
    for (int j = 0; j < 8; ++j)
        out[(size_t)(row0 + rg * 8 + j) * OUT_C + col] = o[j];
}

extern "C" void kernel_launch(void* const* d_in, const int* in_sizes, int n_in,
                              void* d_out, int out_size, void* d_ws, size_t ws_size,
                              hipStream_t stream) {
    const float* x      = (const float*)d_in[0];
    const int*   ei     = (const int*)  d_in[1];
    const float* W_init = (const float*)d_in[2];
    const float* W_self = (const float*)d_in[3];
    const float* W_agg  = (const float*)d_in[4];
    const float* b      = (const float*)d_in[5];
    const float* W_out  = (const float*)d_in[6];
    float* out = (float*)d_out;

    char* ws = (char*)d_ws;
    const size_t KB = 1 << 10;
    int*    cnt    = (int*)(ws + 0);            // 400 KB
    int*    rs     = (int*)(ws + 512 * KB);     // 400 KB
    int*    cursor = (int*)(ws + 1024 * KB);    // 400 KB
    int*    iscan  = (int*)(ws + 1536 * KB);    // 400 KB
    int*    bsum   = (int*)(ws + 2048 * KB);    // 512 B
    int*    csr    = (int*)(ws + 3072 * KB);    // 6.4 MB
    __half* hA     = (__half*)(ws + 10240 * KB); // 12.8 MB
    __half* hB     = (__half*)d_out;             // reuse output buffer (25.6 MB) as fp16 ping-pong

    const int SCAN_BLOCKS = (N_NODES + 1023) / 1024;   // 98

    // CSR build
    hipMemsetAsync(cnt, 0, N_NODES * sizeof(int), stream);
    hipMemsetAsync(cursor, 0, N_NODES * sizeof(int), stream);
    hist_kernel<<<(E_EDGES + 255) / 256, 256, 0, stream>>>(ei, cnt);
    scan_block<<<SCAN_BLOCKS, 1024, 0, stream>>>(cnt, iscan, bsum);
    scan_partials<<<1, 128, 0, stream>>>(bsum, SCAN_BLOCKS);
    finalize_rs<<<SCAN_BLOCKS, 1024, 0, stream>>>(cnt, iscan, bsum, rs);
    fill_csr<<<(E_EDGES + 255) / 256, 256, 0, stream>>>(ei, rs, cursor, csr);

    const int GB = N_NODES / ROWS;   // 3125 (exact)

    // h0 = x @ W_init -> hA (fp16)
    init_gemm<<<GB, 256, 0, stream>>>(x, W_init, hA);

    // layer 0: hA -> hB (d_out as scratch)
    fused_layer<<<GB, 256, 0, stream>>>(hA, rs, cnt, csr,
                                        W_agg + 0 * HID_C * HID_C,
                                        W_self + 0 * HID_C * HID_C,
                                        b + 0 * HID_C, hB);
    // layer 1: hB -> hA
    fused_layer<<<GB, 256, 0, stream>>>(hB, rs, cnt, csr,
                                        W_agg + 1 * HID_C * HID_C,
                                        W_self + 1 * HID_C * HID_C,
                                        b + 1 * HID_C, hA);
    // out = h2 @ W_out (fp32 out)
    out_gemm<<<GB, 256, 0, stream>>>(hA, W_out, out);
}

// Round 5
// 249.077 us; speedup vs baseline: 4.5793x; 1.7173x over previous
//
#include <hip/hip_runtime.h>
#include <hip/hip_fp16.h>

#define N_NODES 100000
#define E_EDGES 1600000
#define IN_C    128
#define HID_C   64
#define OUT_C   64
#define ROWS    32
#define NBUCK   98          // ceil(100000/1024)
#define BSHIFT  10
#define BNODES  1024
#define CAP     24576       // bucket capacity (mean 16384, sigma ~127)
#define CHUNK   4096

typedef _Float16 h2v __attribute__((ext_vector_type(2)));

__device__ __forceinline__ h2v u2h(unsigned int u) { h2v r; __builtin_memcpy(&r, &u, 4); return r; }
__device__ __forceinline__ float dot2(unsigned int a, unsigned int b, float c) {
    return __builtin_amdgcn_fdot2(u2h(a), u2h(b), c, false);
}

// ---------------- phase A: bin edges into buckets (LDS-staged, contiguous writes) ----------------
__global__ __launch_bounds__(256) void bin_kernel(const int* __restrict__ ei,
                                                  int* __restrict__ bucket_cursor,
                                                  unsigned int* __restrict__ gbuck) {
    __shared__ int hist[NBUCK];
    __shared__ int resbase[NBUCK];
    __shared__ int cur[NBUCK];
    __shared__ unsigned int pk[CHUNK];     // 16 KB: (dstlo<<17)|src
    __shared__ unsigned char bk[CHUNK];    // 4 KB
    int tid = threadIdx.x;
    for (int i = tid; i < NBUCK; i += 256) hist[i] = 0;
    __syncthreads();
    int base = blockIdx.x * CHUNK;
    for (int i = tid; i < CHUNK; i += 256) {
        int e = base + i;
        if (e < E_EDGES) {
            int dst = ei[e];
            int src = ei[E_EDGES + e];
            int b = dst >> BSHIFT;
            pk[i] = ((unsigned)(dst & (BNODES - 1)) << 17) | (unsigned)src;
            bk[i] = (unsigned char)b;
            atomicAdd(&hist[b], 1);
        } else bk[i] = 0xFF;
    }
    __syncthreads();
    for (int i = tid; i < NBUCK; i += 256) {
        resbase[i] = atomicAdd(&bucket_cursor[i], hist[i]);
        cur[i] = 0;
    }
    __syncthreads();
    for (int i = tid; i < CHUNK; i += 256) {
        if (bk[i] != 0xFF) {
            int b = bk[i];
            int slot = resbase[b] + atomicAdd(&cur[b], 1);
            if (slot < CAP) gbuck[(size_t)b * CAP + slot] = pk[i];
        }
    }
}

// ---------------- exclusive scan of bucket totals ----------------
__global__ __launch_bounds__(128) void scan_buckets(const int* __restrict__ bucket_cursor,
                                                    int* __restrict__ bucket_base) {
    __shared__ int s[128];
    int t = threadIdx.x;
    int v = (t < NBUCK) ? min(bucket_cursor[t], CAP) : 0;
    s[t] = v;
    __syncthreads();
    for (int off = 1; off < 128; off <<= 1) {
        int u = (t >= off) ? s[t - off] : 0;
        __syncthreads();
        s[t] += u;
        __syncthreads();
    }
    if (t < NBUCK) bucket_base[t] = s[t] - v;
}

// ---------------- phase B: per-bucket local CSR build; single-XCD region writes ----------------
__global__ __launch_bounds__(256) void build_bucket(const unsigned int* __restrict__ gbuck,
                                                    const int* __restrict__ bucket_cursor,
                                                    const int* __restrict__ bucket_base,
                                                    int* __restrict__ csr,
                                                    int* __restrict__ cnt,
                                                    int* __restrict__ rs) {
    __shared__ int lcnt[BNODES];
    __shared__ int lpos[BNODES];
    __shared__ int lcur[BNODES];
    __shared__ int ss[256];
    int t = threadIdx.x;
    int b = blockIdx.x;
    int gnode = b * BNODES;
    int nn = min(BNODES, N_NODES - gnode);
    int ec = min(bucket_cursor[b], CAP);
    int bb = bucket_base[b];
    for (int i = t; i < BNODES; i += 256) { lcnt[i] = 0; lcur[i] = 0; }
    __syncthreads();
    const unsigned int* mybuck = gbuck + (size_t)b * CAP;
    for (int i = t; i < ec; i += 256)
        atomicAdd(&lcnt[mybuck[i] >> 17], 1);
    __syncthreads();
    // exclusive scan of lcnt[1024] via 256 threads x 4
    int c0 = lcnt[4*t], c1 = lcnt[4*t+1], c2 = lcnt[4*t+2], c3 = lcnt[4*t+3];
    int tsum = c0 + c1 + c2 + c3;
    ss[t] = tsum;
    __syncthreads();
    for (int off = 1; off < 256; off <<= 1) {
        int u = (t >= off) ? ss[t - off] : 0;
        __syncthreads();
        ss[t] += u;
        __syncthreads();
    }
    int ex = ss[t] - tsum;
    lpos[4*t] = ex; lpos[4*t+1] = ex + c0; lpos[4*t+2] = ex + c0 + c1; lpos[4*t+3] = ex + c0 + c1 + c2;
    __syncthreads();
    for (int n = t; n < nn; n += 256) {
        cnt[gnode + n] = lcnt[n];
        rs[gnode + n] = bb + lpos[n];
    }
    for (int i = t; i < ec; i += 256) {
        unsigned int p = mybuck[i];
        int dl = p >> 17;
        int src = p & 0x1FFFF;
        int slot = lpos[dl] + atomicAdd(&lcur[dl], 1);
        csr[bb + slot] = src;
    }
}

// ---------------- h0 = x @ W_init (dot2), fp16 out ----------------
__global__ __launch_bounds__(256) void init_gemm(const float* __restrict__ x,
                                                 const float* __restrict__ W,
                                                 __half* __restrict__ h) {
    __shared__ unsigned int sW2[64 * 64];      // 16 KB, [k2*64+col]
    __shared__ unsigned int sx2[ROWS][64];     // 8 KB
    int tid = threadIdx.x;
    __half* w_h = (__half*)sW2;
    for (int i = tid; i < IN_C * HID_C; i += 256) {
        int k = i >> 6, col = i & 63;
        w_h[(k >> 1) * 128 + col * 2 + (k & 1)] = __float2half(W[i]);
    }
    int row0 = blockIdx.x * ROWS;
    const float4* x4 = (const float4*)x;
    for (int i = tid; i < ROWS * IN_C / 4; i += 256) {
        int r = i >> 5, q = i & 31;
        float4 f = x4[(size_t)(row0 + r) * 32 + q];
        __half2 h0 = __floats2half2_rn(f.x, f.y);
        __half2 h1 = __floats2half2_rn(f.z, f.w);
        sx2[r][q * 2]     = *(unsigned int*)&h0;
        sx2[r][q * 2 + 1] = *(unsigned int*)&h1;
    }
    __syncthreads();
    int col = tid & 63, rg = tid >> 6;
    float o[8];
    #pragma unroll
    for (int j = 0; j < 8; ++j) o[j] = 0.f;
    for (int k2 = 0; k2 < 64; ++k2) {
        unsigned wv = sW2[k2 * 64 + col];
        #pragma unroll
        for (int j = 0; j < 8; ++j)
            o[j] = dot2(sx2[rg * 8 + j][k2], wv, o[j]);
    }
    #pragma unroll
    for (int j = 0; j < 8; ++j)
        h[(size_t)(row0 + rg * 8 + j) * HID_C + col] = __float2half(o[j]);
}

// ---------------- fused: gather-mean (4 edges x 16 lanes x 4ch) + dot2 GEMM + ReLU ----------------
__global__ __launch_bounds__(256) void fused_layer(const __half* __restrict__ h,
                                                   const int* __restrict__ rs,
                                                   const int* __restrict__ cnt,
                                                   const int* __restrict__ csr,
                                                   const float* __restrict__ Wa,
                                                   const float* __restrict__ Ws,
                                                   const float* __restrict__ bias,
                                                   __half* __restrict__ hout) {
    __shared__ unsigned int sWa2[32 * 64];   // 8 KB
    __shared__ unsigned int sWs2[32 * 64];   // 8 KB
    __shared__ unsigned int sA2[ROWS][32];   // 4 KB
    __shared__ unsigned int sH2[ROWS][32];   // 4 KB
    int tid = threadIdx.x;
    __half* wa_h = (__half*)sWa2;
    __half* ws_h = (__half*)sWs2;
    for (int i = tid; i < HID_C * HID_C; i += 256) {
        int k = i >> 6, col = i & 63;
        int li = (k >> 1) * 128 + col * 2 + (k & 1);
        wa_h[li] = __float2half(Wa[i]);
        ws_h[li] = __float2half(Ws[i]);
    }
    int row0 = blockIdx.x * ROWS;
    int wave = tid >> 6, lane = tid & 63;
    int g4 = lane >> 4;       // edge slot 0..3
    int c16 = lane & 15;      // channel block: channels [4*c16, 4*c16+4)
    const uint2* h2u = (const uint2*)h;   // row = 16 uint2
    for (int i = 0; i < 8; ++i) {
        int rl = wave * 8 + i;
        int row = row0 + rl;
        int start = __builtin_amdgcn_readfirstlane(rs[row]);
        int d     = __builtin_amdgcn_readfirstlane(cnt[row]);
        uint2 selfv = h2u[(size_t)row * 16 + c16];
        float a0 = 0.f, a1 = 0.f, a2 = 0.f, a3 = 0.f;
        int j = 0;
        for (; j + 16 <= d; j += 16) {        // full chunks: no predication
            uint2 v[4];
            #pragma unroll
            for (int s = 0; s < 4; ++s) {
                int src = csr[start + j + s * 4 + g4];
                v[s] = h2u[(size_t)src * 16 + c16];
            }
            __half2 p01 = __floats2half2_rn(0.f, 0.f), p23 = p01;
            #pragma unroll
            for (int s = 0; s < 4; ++s) {
                p01 += *(__half2*)&v[s].x;
                p23 += *(__half2*)&v[s].y;
            }
            a0 += __low2float(p01); a1 += __high2float(p01);
            a2 += __low2float(p23); a3 += __high2float(p23);
        }
        if (j < d) {                          // tail chunk: predicated
            int dm1 = d - 1;
            uint2 v[4]; bool ok[4];
            #pragma unroll
            for (int s = 0; s < 4; ++s) {
                int e = j + s * 4 + g4;
                ok[s] = e < d;
                int src = csr[start + min(e, dm1)];
                v[s] = h2u[(size_t)src * 16 + c16];
            }
            __half2 p01 = __floats2half2_rn(0.f, 0.f), p23 = p01;
            #pragma unroll
            for (int s = 0; s < 4; ++s) {
                unsigned vx = ok[s] ? v[s].x : 0u;
                unsigned vy = ok[s] ? v[s].y : 0u;
                p01 += *(__half2*)&vx;
                p23 += *(__half2*)&vy;
            }
            a0 += __low2float(p01); a1 += __high2float(p01);
            a2 += __low2float(p23); a3 += __high2float(p23);
        }
        a0 += __shfl_xor(a0, 16); a1 += __shfl_xor(a1, 16);
        a2 += __shfl_xor(a2, 16); a3 += __shfl_xor(a3, 16);
        a0 += __shfl_xor(a0, 32); a1 += __shfl_xor(a1, 32);
        a2 += __shfl_xor(a2, 32); a3 += __shfl_xor(a3, 32);
        if (lane < 16) {
            float inv = 1.f / fmaxf((float)d, 1.f);
            __half2 ha = __floats2half2_rn(a0 * inv, a1 * inv);
            __half2 hb = __floats2half2_rn(a2 * inv, a3 * inv);
            sA2[rl][c16 * 2]     = *(unsigned int*)&ha;
            sA2[rl][c16 * 2 + 1] = *(unsigned int*)&hb;
            sH2[rl][c16 * 2]     = selfv.x;
            sH2[rl][c16 * 2 + 1] = selfv.y;
        }
    }
    __syncthreads();
    int col = lane, rg = wave;
    float bv = bias[col];
    float o[8];
    #pragma unroll
    for (int j = 0; j < 8; ++j) o[j] = bv;
    for (int k2 = 0; k2 < 32; ++k2) {
        unsigned wA = sWa2[k2 * 64 + col];
        unsigned wS = sWs2[k2 * 64 + col];
        #pragma unroll
        for (int j = 0; j < 8; ++j) {
            int r = rg * 8 + j;
            o[j] = dot2(sA2[r][k2], wA, o[j]);
            o[j] = dot2(sH2[r][k2], wS, o[j]);
        }
    }
    #pragma unroll
    for (int j = 0; j < 8; ++j)
        hout[(size_t)(row0 + rg * 8 + j) * HID_C + col] = __float2half(fmaxf(o[j], 0.f));
}

// ---------------- out = h @ W_out (dot2), fp32 out ----------------
__global__ __launch_bounds__(256) void out_gemm(const __half* __restrict__ h,
                                                const float* __restrict__ W,
                                                float* __restrict__ out) {
    __shared__ unsigned int sW2[32 * 64];    // 8 KB
    __shared__ unsigned int sH2[ROWS][32];   // 4 KB
    int tid = threadIdx.x;
    __half* w_h = (__half*)sW2;
    for (int i = tid; i < HID_C * OUT_C; i += 256) {
        int k = i >> 6, col = i & 63;
        w_h[(k >> 1) * 128 + col * 2 + (k & 1)] = __float2half(W[i]);
    }
    int row0 = blockIdx.x * ROWS;
    const unsigned int* hu = (const unsigned int*)h;
    for (int i = tid; i < ROWS * 32; i += 256) {
        int r = i >> 5, q = i & 31;
        sH2[r][q] = hu[(size_t)(row0 + r) * 32 + q];
    }
    __syncthreads();
    int col = tid & 63, rg = tid >> 6;
    float o[8];
    #pragma unroll
    for (int j = 0; j < 8; ++j) o[j] = 0.f;
    for (int k2 = 0; k2 < 32; ++k2) {
        unsigned wv = sW2[k2 * 64 + col];
        #pragma unroll
        for (int j = 0; j < 8; ++j)
            o[j] = dot2(sH2[rg * 8 + j][k2], wv, o[j]);
    }
    #pragma unroll
    for (int j = 0; j < 8; ++j)
        out[(size_t)(row0 + rg * 8 + j) * OUT_C + col] = o[j];
}

extern "C" void kernel_launch(void* const* d_in, const int* in_sizes, int n_in,
                              void* d_out, int out_size, void* d_ws, size_t ws_size,
                              hipStream_t stream) {
    const float* x      = (const float*)d_in[0];
    const int*   ei     = (const int*)  d_in[1];
    const float* W_init = (const float*)d_in[2];
    const float* W_self = (const float*)d_in[3];
    const float* W_agg  = (const float*)d_in[4];
    const float* b      = (const float*)d_in[5];
    const float* W_out  = (const float*)d_in[6];
    float* out = (float*)d_out;

    char* ws = (char*)d_ws;
    const size_t KB = 1 << 10;
    int* bucket_cursor     = (int*)(ws + 0);
    int* bucket_base       = (int*)(ws + 1 * KB);
    int* cnt               = (int*)(ws + 4 * KB);          // 400 KB
    int* rs                = (int*)(ws + 512 * KB);        // 400 KB
    int* csr               = (int*)(ws + 1024 * KB);       // 6.4 MB
    unsigned int* gbuck    = (unsigned int*)(ws + 8192 * KB);   // 98*24576*4 = 9.63 MB
    __half* hA             = (__half*)(ws + 18432 * KB);   // 12.8 MB
    __half* hB             = (__half*)d_out;               // reuse output buffer as fp16 ping-pong

    // CSR build: bin -> scan -> build (writes csr, cnt, rs)
    hipMemsetAsync(bucket_cursor, 0, NBUCK * sizeof(int), stream);
    bin_kernel<<<(E_EDGES + CHUNK - 1) / CHUNK, 256, 0, stream>>>(ei, bucket_cursor, gbuck);
    scan_buckets<<<1, 128, 0, stream>>>(bucket_cursor, bucket_base);
    build_bucket<<<NBUCK, 256, 0, stream>>>(gbuck, bucket_cursor, bucket_base, csr, cnt, rs);

    const int GB = N_NODES / ROWS;   // 3125 (exact)

    init_gemm<<<GB, 256, 0, stream>>>(x, W_init, hA);

    fused_layer<<<GB, 256, 0, stream>>>(hA, rs, cnt, csr,
                                        W_agg + 0 * HID_C * HID_C,
                                        W_self + 0 * HID_C * HID_C,
                                        b + 0 * HID_C, hB);
    fused_layer<<<GB, 256, 0, stream>>>(hB, rs, cnt, csr,
                                        W_agg + 1 * HID_C * HID_C,
                                        W_self + 1 * HID_C * HID_C,
                                        b + 1 * HID_C, hA);

    out_gemm<<<GB, 256, 0, stream>>>(hA, W_out, out);
}

// Round 6
// 201.979 us; speedup vs baseline: 5.6470x; 1.2332x over previous
//
#include <hip/hip_runtime.h>
#include <hip/hip_fp16.h>

#define N_NODES 100000
#define E_EDGES 1600000
#define IN_C    128
#define HID_C   64
#define OUT_C   64
#define ROWS    32
#define NBUCK   98          // ceil(100000/1024)
#define BSHIFT  10
#define BNODES  1024
#define CAP     24576
#define CHUNK   4096

typedef _Float16 f16x8 __attribute__((ext_vector_type(8)));
typedef float    f32x4 __attribute__((ext_vector_type(4)));
#define MFMA16(a, b, c) __builtin_amdgcn_mfma_f32_16x16x32_f16(a, b, c, 0, 0, 0)

// ---------------- phase A: bin edges into buckets ----------------
__global__ __launch_bounds__(256) void bin_kernel(const int* __restrict__ ei,
                                                  int* __restrict__ bucket_cursor,
                                                  unsigned int* __restrict__ gbuck) {
    __shared__ int hist[NBUCK];
    __shared__ int resbase[NBUCK];
    __shared__ int cur[NBUCK];
    __shared__ unsigned int pk[CHUNK];
    __shared__ unsigned char bk[CHUNK];
    int tid = threadIdx.x;
    for (int i = tid; i < NBUCK; i += 256) hist[i] = 0;
    __syncthreads();
    int base = blockIdx.x * CHUNK;
    for (int i = tid; i < CHUNK; i += 256) {
        int e = base + i;
        if (e < E_EDGES) {
            int dst = ei[e];
            int src = ei[E_EDGES + e];
            int b = dst >> BSHIFT;
            pk[i] = ((unsigned)(dst & (BNODES - 1)) << 17) | (unsigned)src;
            bk[i] = (unsigned char)b;
            atomicAdd(&hist[b], 1);
        } else bk[i] = 0xFF;
    }
    __syncthreads();
    for (int i = tid; i < NBUCK; i += 256) {
        resbase[i] = atomicAdd(&bucket_cursor[i], hist[i]);
        cur[i] = 0;
    }
    __syncthreads();
    for (int i = tid; i < CHUNK; i += 256) {
        if (bk[i] != 0xFF) {
            int b = bk[i];
            int slot = resbase[b] + atomicAdd(&cur[b], 1);
            if (slot < CAP) gbuck[(size_t)b * CAP + slot] = pk[i];
        }
    }
}

// ---------------- exclusive scan of bucket totals ----------------
__global__ __launch_bounds__(128) void scan_buckets(const int* __restrict__ bucket_cursor,
                                                    int* __restrict__ bucket_base) {
    __shared__ int s[128];
    int t = threadIdx.x;
    int v = (t < NBUCK) ? min(bucket_cursor[t], CAP) : 0;
    s[t] = v;
    __syncthreads();
    for (int off = 1; off < 128; off <<= 1) {
        int u = (t >= off) ? s[t - off] : 0;
        __syncthreads();
        s[t] += u;
        __syncthreads();
    }
    if (t < NBUCK) bucket_base[t] = s[t] - v;
}

// ---------------- phase B: per-bucket local CSR build ----------------
__global__ __launch_bounds__(256) void build_bucket(const unsigned int* __restrict__ gbuck,
                                                    const int* __restrict__ bucket_cursor,
                                                    const int* __restrict__ bucket_base,
                                                    int* __restrict__ csr,
                                                    int* __restrict__ cnt,
                                                    int* __restrict__ rs) {
    __shared__ int lcnt[BNODES];
    __shared__ int lpos[BNODES];
    __shared__ int lcur[BNODES];
    __shared__ int ss[256];
    int t = threadIdx.x;
    int b = blockIdx.x;
    int gnode = b * BNODES;
    int nn = min(BNODES, N_NODES - gnode);
    int ec = min(bucket_cursor[b], CAP);
    int bb = bucket_base[b];
    for (int i = t; i < BNODES; i += 256) { lcnt[i] = 0; lcur[i] = 0; }
    __syncthreads();
    const unsigned int* mybuck = gbuck + (size_t)b * CAP;
    for (int i = t; i < ec; i += 256)
        atomicAdd(&lcnt[mybuck[i] >> 17], 1);
    __syncthreads();
    int c0 = lcnt[4*t], c1 = lcnt[4*t+1], c2 = lcnt[4*t+2], c3 = lcnt[4*t+3];
    int tsum = c0 + c1 + c2 + c3;
    ss[t] = tsum;
    __syncthreads();
    for (int off = 1; off < 256; off <<= 1) {
        int u = (t >= off) ? ss[t - off] : 0;
        __syncthreads();
        ss[t] += u;
        __syncthreads();
    }
    int ex = ss[t] - tsum;
    lpos[4*t] = ex; lpos[4*t+1] = ex + c0; lpos[4*t+2] = ex + c0 + c1; lpos[4*t+3] = ex + c0 + c1 + c2;
    __syncthreads();
    for (int n = t; n < nn; n += 256) {
        cnt[gnode + n] = lcnt[n];
        rs[gnode + n] = bb + lpos[n];
    }
    for (int i = t; i < ec; i += 256) {
        unsigned int p = mybuck[i];
        int dl = p >> 17;
        int src = p & 0x1FFFF;
        int slot = lpos[dl] + atomicAdd(&lcur[dl], 1);
        csr[bb + slot] = src;
    }
}

// MFMA tile: each of 4 waves computes 16x32 of the 32x64 block output.
// sA: [32][LDA] f16 (rows x K), sBt: [64][LDA] f16 (cols x K), LDA = K+8.
template<int K>
__device__ __forceinline__ void mfma_tile(const _Float16* sA, const _Float16* sBt,
                                          int lane, int wave, f32x4 acc[2]) {
    const int LDA = K + 8;
    int r0 = (wave >> 1) * 16;
    int wc = wave & 1;
    int m = lane & 15, kg = lane >> 4;
    acc[0] = (f32x4){0.f, 0.f, 0.f, 0.f};
    acc[1] = (f32x4){0.f, 0.f, 0.f, 0.f};
    #pragma unroll
    for (int ks = 0; ks < K / 32; ++ks) {
        f16x8 a = *(const f16x8*)&sA[(r0 + m) * LDA + 32 * ks + 8 * kg];
        #pragma unroll
        for (int nt = 0; nt < 2; ++nt) {
            f16x8 b = *(const f16x8*)&sBt[(wc * 32 + nt * 16 + m) * LDA + 32 * ks + 8 * kg];
            acc[nt] = MFMA16(a, b, acc[nt]);
        }
    }
}

// ---------------- h0 = x @ W_init (MFMA), fp16 out ----------------
__global__ __launch_bounds__(256) void init_gemm(const float* __restrict__ x,
                                                 const float* __restrict__ W,
                                                 __half* __restrict__ h) {
    __shared__ _Float16 sA[ROWS][IN_C + 8];    // 8.5 KB
    __shared__ _Float16 sBt[HID_C][IN_C + 8];  // 17 KB
    int tid = threadIdx.x;
    // stage W transposed: sBt[col][k]
    for (int i = tid; i < IN_C * HID_C; i += 256) {
        int k = i >> 6, col = i & 63;
        sBt[col][k] = (_Float16)W[i];
    }
    int row0 = blockIdx.x * ROWS;
    const float4* x4 = (const float4*)x;
    for (int i = tid; i < ROWS * IN_C / 4; i += 256) {
        int r = i >> 5, q = i & 31;     // 32 float4 per row
        float4 f = x4[(size_t)(row0 + r) * 32 + q];
        sA[r][q * 4]     = (_Float16)f.x;
        sA[r][q * 4 + 1] = (_Float16)f.y;
        sA[r][q * 4 + 2] = (_Float16)f.z;
        sA[r][q * 4 + 3] = (_Float16)f.w;
    }
    __syncthreads();
    int lane = tid & 63, wave = tid >> 6;
    f32x4 acc[2];
    mfma_tile<IN_C>(&sA[0][0], &sBt[0][0], lane, wave, acc);
    int m = lane & 15, rg = lane >> 4;
    int r0 = (wave >> 1) * 16, wc = wave & 1;
    #pragma unroll
    for (int nt = 0; nt < 2; ++nt) {
        int col = wc * 32 + nt * 16 + m;
        #pragma unroll
        for (int i = 0; i < 4; ++i) {
            int row = row0 + r0 + rg * 4 + i;
            h[(size_t)row * HID_C + col] = __float2half(acc[nt][i]);
        }
    }
}

// ---------------- fused: gather-mean + MFMA combine + ReLU ----------------
__global__ __launch_bounds__(256) void fused_layer(const __half* __restrict__ h,
                                                   const int* __restrict__ rs,
                                                   const int* __restrict__ cnt,
                                                   const int* __restrict__ csr,
                                                   const float* __restrict__ Wa,
                                                   const float* __restrict__ Ws,
                                                   const float* __restrict__ bias,
                                                   __half* __restrict__ hout) {
    __shared__ _Float16 sA[ROWS][136];     // [row][k]: k<64 agg, k>=64 self. 8.5 KB
    __shared__ _Float16 sBt[HID_C][136];   // [col][k]: k<64 Wa, k>=64 Ws. 17 KB
    int tid = threadIdx.x;
    // stage stacked weights transposed
    for (int i = tid; i < 128 * HID_C; i += 256) {
        int k = i >> 6, col = i & 63;
        float w = (k < 64) ? Wa[k * 64 + col] : Ws[(k - 64) * 64 + col];
        sBt[col][k] = (_Float16)w;
    }
    int row0 = blockIdx.x * ROWS;
    int wave = tid >> 6, lane = tid & 63;
    int g4 = lane >> 4;       // edge slot 0..3
    int c16 = lane & 15;      // channel block: channels [4*c16, 4*c16+4)
    const uint2* h2u = (const uint2*)h;   // row = 16 uint2
    for (int i = 0; i < 8; ++i) {
        int rl = wave * 8 + i;
        int row = row0 + rl;
        int start = __builtin_amdgcn_readfirstlane(rs[row]);
        int d     = __builtin_amdgcn_readfirstlane(cnt[row]);
        uint2 selfv = h2u[(size_t)row * 16 + c16];
        float a0 = 0.f, a1 = 0.f, a2 = 0.f, a3 = 0.f;
        int j = 0;
        for (; j + 16 <= d; j += 16) {        // full chunks: no predication
            uint2 v[4];
            #pragma unroll
            for (int s = 0; s < 4; ++s) {
                int src = csr[start + j + s * 4 + g4];
                v[s] = h2u[(size_t)src * 16 + c16];
            }
            __half2 p01 = __floats2half2_rn(0.f, 0.f), p23 = p01;
            #pragma unroll
            for (int s = 0; s < 4; ++s) {
                p01 += *(__half2*)&v[s].x;
                p23 += *(__half2*)&v[s].y;
            }
            a0 += __low2float(p01); a1 += __high2float(p01);
            a2 += __low2float(p23); a3 += __high2float(p23);
        }
        if (j < d) {                          // tail chunk: predicated
            int dm1 = d - 1;
            uint2 v[4]; bool ok[4];
            #pragma unroll
            for (int s = 0; s < 4; ++s) {
                int e = j + s * 4 + g4;
                ok[s] = e < d;
                int src = csr[start + min(e, dm1)];
                v[s] = h2u[(size_t)src * 16 + c16];
            }
            __half2 p01 = __floats2half2_rn(0.f, 0.f), p23 = p01;
            #pragma unroll
            for (int s = 0; s < 4; ++s) {
                unsigned vx = ok[s] ? v[s].x : 0u;
                unsigned vy = ok[s] ? v[s].y : 0u;
                p01 += *(__half2*)&vx;
                p23 += *(__half2*)&vy;
            }
            a0 += __low2float(p01); a1 += __high2float(p01);
            a2 += __low2float(p23); a3 += __high2float(p23);
        }
        a0 += __shfl_xor(a0, 16); a1 += __shfl_xor(a1, 16);
        a2 += __shfl_xor(a2, 16); a3 += __shfl_xor(a3, 16);
        a0 += __shfl_xor(a0, 32); a1 += __shfl_xor(a1, 32);
        a2 += __shfl_xor(a2, 32); a3 += __shfl_xor(a3, 32);
        if (lane < 16) {
            float inv = 1.f / fmaxf((float)d, 1.f);
            __half2 ha = __floats2half2_rn(a0 * inv, a1 * inv);
            __half2 hb = __floats2half2_rn(a2 * inv, a3 * inv);
            uint2 agg2; agg2.x = *(unsigned*)&ha; agg2.y = *(unsigned*)&hb;
            *(uint2*)&sA[rl][4 * c16]      = agg2;   // agg -> k [0,64)
            *(uint2*)&sA[rl][64 + 4 * c16] = selfv;  // self -> k [64,128)
        }
    }
    __syncthreads();
    f32x4 acc[2];
    mfma_tile<128>(&sA[0][0], &sBt[0][0], lane, wave, acc);
    int m = lane & 15, rg = lane >> 4;
    int r0 = (wave >> 1) * 16, wc = wave & 1;
    #pragma unroll
    for (int nt = 0; nt < 2; ++nt) {
        int col = wc * 32 + nt * 16 + m;
        float bv = bias[col];
        #pragma unroll
        for (int i = 0; i < 4; ++i) {
            int row = row0 + r0 + rg * 4 + i;
            float v = fmaxf(acc[nt][i] + bv, 0.f);
            hout[(size_t)row * HID_C + col] = __float2half(v);
        }
    }
}

// ---------------- out = h @ W_out (MFMA), fp32 out ----------------
__global__ __launch_bounds__(256) void out_gemm(const __half* __restrict__ h,
                                                const float* __restrict__ W,
                                                float* __restrict__ out) {
    __shared__ _Float16 sA[ROWS][HID_C + 8];    // 4.5 KB
    __shared__ _Float16 sBt[OUT_C][HID_C + 8];  // 9 KB
    int tid = threadIdx.x;
    for (int i = tid; i < HID_C * OUT_C; i += 256) {
        int k = i >> 6, col = i & 63;
        sBt[col][k] = (_Float16)W[i];
    }
    int row0 = blockIdx.x * ROWS;
    const unsigned int* hu = (const unsigned int*)h;
    for (int i = tid; i < ROWS * 32; i += 256) {
        int r = i >> 5, q = i & 31;
        *(unsigned int*)&sA[r][q * 2] = hu[(size_t)(row0 + r) * 32 + q];
    }
    __syncthreads();
    int lane = tid & 63, wave = tid >> 6;
    f32x4 acc[2];
    mfma_tile<HID_C>(&sA[0][0], &sBt[0][0], lane, wave, acc);
    int m = lane & 15, rg = lane >> 4;
    int r0 = (wave >> 1) * 16, wc = wave & 1;
    #pragma unroll
    for (int nt = 0; nt < 2; ++nt) {
        int col = wc * 32 + nt * 16 + m;
        #pragma unroll
        for (int i = 0; i < 4; ++i) {
            int row = row0 + r0 + rg * 4 + i;
            out[(size_t)row * OUT_C + col] = acc[nt][i];
        }
    }
}

extern "C" void kernel_launch(void* const* d_in, const int* in_sizes, int n_in,
                              void* d_out, int out_size, void* d_ws, size_t ws_size,
                              hipStream_t stream) {
    const float* x      = (const float*)d_in[0];
    const int*   ei     = (const int*)  d_in[1];
    const float* W_init = (const float*)d_in[2];
    const float* W_self = (const float*)d_in[3];
    const float* W_agg  = (const float*)d_in[4];
    const float* b      = (const float*)d_in[5];
    const float* W_out  = (const float*)d_in[6];
    float* out = (float*)d_out;

    char* ws = (char*)d_ws;
    const size_t KB = 1 << 10;
    int* bucket_cursor  = (int*)(ws + 0);
    int* bucket_base    = (int*)(ws + 1 * KB);
    int* cnt            = (int*)(ws + 4 * KB);
    int* rs             = (int*)(ws + 512 * KB);
    int* csr            = (int*)(ws + 1024 * KB);              // 6.4 MB
    unsigned int* gbuck = (unsigned int*)(ws + 8192 * KB);     // 9.63 MB
    __half* hA          = (__half*)(ws + 18432 * KB);          // 12.8 MB
    __half* hB          = (__half*)d_out;                      // reuse output buffer

    // CSR build: bin -> scan -> build
    hipMemsetAsync(bucket_cursor, 0, NBUCK * sizeof(int), stream);
    bin_kernel<<<(E_EDGES + CHUNK - 1) / CHUNK, 256, 0, stream>>>(ei, bucket_cursor, gbuck);
    scan_buckets<<<1, 128, 0, stream>>>(bucket_cursor, bucket_base);
    build_bucket<<<NBUCK, 256, 0, stream>>>(gbuck, bucket_cursor, bucket_base, csr, cnt, rs);

    const int GB = N_NODES / ROWS;   // 3125 (exact)

    init_gemm<<<GB, 256, 0, stream>>>(x, W_init, hA);

    fused_layer<<<GB, 256, 0, stream>>>(hA, rs, cnt, csr,
                                        W_agg + 0 * HID_C * HID_C,
                                        W_self + 0 * HID_C * HID_C,
                                        b + 0 * HID_C, hB);
    fused_layer<<<GB, 256, 0, stream>>>(hB, rs, cnt, csr,
                                        W_agg + 1 * HID_C * HID_C,
                                        W_self + 1 * HID_C * HID_C,
                                        b + 1 * HID_C, hA);

    out_gemm<<<GB, 256, 0, stream>>>(hA, W_out, out);
}

// Round 7
// 168.408 us; speedup vs baseline: 6.7728x; 1.1993x over previous
//
#include <hip/hip_runtime.h>
#include <hip/hip_fp16.h>

#define N_NODES 100000
#define E_EDGES 1600000
#define IN_C    128
#define HID_C   64
#define OUT_C   64
#define ROWS    32
#define NBUCK   391         // ceil(100000/256)
#define BSHIFT  8
#define BNODES  256
#define CAP     5120        // mean 4096, sigma ~64
#define CHUNK   4096

typedef _Float16 f16x8 __attribute__((ext_vector_type(8)));
typedef float    f32x4 __attribute__((ext_vector_type(4)));
#define MFMA16(a, b, c) __builtin_amdgcn_mfma_f32_16x16x32_f16(a, b, c, 0, 0, 0)

// ---------------- phase A: bin edges into buckets ----------------
__global__ __launch_bounds__(256) void bin_kernel(const int* __restrict__ ei,
                                                  int* __restrict__ bucket_cursor,
                                                  unsigned int* __restrict__ gbuck) {
    __shared__ int hist[NBUCK];
    __shared__ int resbase[NBUCK];
    __shared__ int cur[NBUCK];
    __shared__ unsigned int pk[CHUNK];       // 16 KB: (dstlo<<17)|src
    __shared__ unsigned short bk[CHUNK];     // 8 KB
    int tid = threadIdx.x;
    for (int i = tid; i < NBUCK; i += 256) hist[i] = 0;
    __syncthreads();
    int base = blockIdx.x * CHUNK;
    for (int i = tid; i < CHUNK; i += 256) {
        int e = base + i;
        if (e < E_EDGES) {
            int dst = ei[e];
            int src = ei[E_EDGES + e];
            int b = dst >> BSHIFT;
            pk[i] = ((unsigned)(dst & (BNODES - 1)) << 17) | (unsigned)src;
            bk[i] = (unsigned short)b;
            atomicAdd(&hist[b], 1);
        } else bk[i] = 0xFFFF;
    }
    __syncthreads();
    for (int i = tid; i < NBUCK; i += 256) {
        resbase[i] = atomicAdd(&bucket_cursor[i], hist[i]);
        cur[i] = 0;
    }
    __syncthreads();
    for (int i = tid; i < CHUNK; i += 256) {
        if (bk[i] != 0xFFFF) {
            int b = bk[i];
            int slot = resbase[b] + atomicAdd(&cur[b], 1);
            if (slot < CAP) gbuck[(size_t)b * CAP + slot] = pk[i];
        }
    }
}

// ---------------- exclusive scan of bucket totals ----------------
__global__ __launch_bounds__(512) void scan_buckets(const int* __restrict__ bucket_cursor,
                                                    int* __restrict__ bucket_base) {
    __shared__ int s[512];
    int t = threadIdx.x;
    int v = (t < NBUCK) ? min(bucket_cursor[t], CAP) : 0;
    s[t] = v;
    __syncthreads();
    for (int off = 1; off < 512; off <<= 1) {
        int u = (t >= off) ? s[t - off] : 0;
        __syncthreads();
        s[t] += u;
        __syncthreads();
    }
    if (t < NBUCK) bucket_base[t] = s[t] - v;
}

// ---------------- phase B: per-bucket local CSR build (256 nodes/bucket) ----------------
__global__ __launch_bounds__(256) void build_bucket(const unsigned int* __restrict__ gbuck,
                                                    const int* __restrict__ bucket_cursor,
                                                    const int* __restrict__ bucket_base,
                                                    int* __restrict__ csr,
                                                    int2* __restrict__ rc) {
    __shared__ int lcnt[BNODES];
    __shared__ int lpos[BNODES];
    __shared__ int lcur[BNODES];
    __shared__ int ss[256];
    int t = threadIdx.x;
    int b = blockIdx.x;
    int gnode = b * BNODES;
    int nn = min(BNODES, N_NODES - gnode);
    int ec = min(bucket_cursor[b], CAP);
    int bb = bucket_base[b];
    lcnt[t] = 0; lcur[t] = 0;
    __syncthreads();
    const unsigned int* mybuck = gbuck + (size_t)b * CAP;
    for (int i = t; i < ec; i += 256)
        atomicAdd(&lcnt[mybuck[i] >> 17], 1);
    __syncthreads();
    int c = lcnt[t];
    ss[t] = c;
    __syncthreads();
    for (int off = 1; off < 256; off <<= 1) {
        int u = (t >= off) ? ss[t - off] : 0;
        __syncthreads();
        ss[t] += u;
        __syncthreads();
    }
    int ex = ss[t] - c;
    lpos[t] = ex;
    if (t < nn) rc[gnode + t] = make_int2(bb + ex, c);
    __syncthreads();
    for (int i = t; i < ec; i += 256) {
        unsigned int p = mybuck[i];
        int dl = p >> 17;
        int slot = lpos[dl] + atomicAdd(&lcur[dl], 1);
        csr[bb + slot] = (int)(p & 0x1FFFF);
    }
}

// ---------------- pre-transpose all weights to fp16 [col][k] padded layouts ----------------
// wtr element layout: [0,8704) init 64x136 | [8704,17408) layer0 | [17408,26112) layer1 | [26112,30720) out 64x72
__global__ __launch_bounds__(256) void transpose_weights(const float* __restrict__ Wi,
                                                         const float* __restrict__ Wsf,
                                                         const float* __restrict__ Waf,
                                                         const float* __restrict__ Wo,
                                                         _Float16* __restrict__ wtr) {
    int t = blockIdx.x * 256 + threadIdx.x;
    if (t < 8192) {
        int k = t >> 6, col = t & 63;
        wtr[col * 136 + k] = (_Float16)Wi[t];
    } else if (t < 24576) {
        int u = t - 8192; int l = u >> 13; int v = u & 8191;
        int k = v >> 6, col = v & 63;
        float w = (k < 64) ? Waf[l * 4096 + k * 64 + col] : Wsf[l * 4096 + (k - 64) * 64 + col];
        wtr[8704 + l * 8704 + col * 136 + k] = (_Float16)w;
    } else if (t < 28672) {
        int u = t - 24576; int k = u >> 6, col = u & 63;
        wtr[26112 + col * 72 + k] = (_Float16)Wo[u];
    }
}

// MFMA tile: each of 4 waves computes 16x32 of the 32x64 block output. LDA = K+8.
template<int K>
__device__ __forceinline__ void mfma_tile(const _Float16* sA, const _Float16* sBt,
                                          int lane, int wave, f32x4 acc[2]) {
    const int LDA = K + 8;
    int r0 = (wave >> 1) * 16;
    int wc = wave & 1;
    int m = lane & 15, kg = lane >> 4;
    acc[0] = (f32x4){0.f, 0.f, 0.f, 0.f};
    acc[1] = (f32x4){0.f, 0.f, 0.f, 0.f};
    #pragma unroll
    for (int ks = 0; ks < K / 32; ++ks) {
        f16x8 a = *(const f16x8*)&sA[(r0 + m) * LDA + 32 * ks + 8 * kg];
        #pragma unroll
        for (int nt = 0; nt < 2; ++nt) {
            f16x8 b = *(const f16x8*)&sBt[(wc * 32 + nt * 16 + m) * LDA + 32 * ks + 8 * kg];
            acc[nt] = MFMA16(a, b, acc[nt]);
        }
    }
}

// ---------------- h0 = x @ W_init (MFMA), fp16 out ----------------
__global__ __launch_bounds__(256) void init_gemm(const float* __restrict__ x,
                                                 const float4* __restrict__ wtrI,
                                                 __half* __restrict__ h) {
    __shared__ _Float16 sA[ROWS][IN_C + 8];
    __shared__ _Float16 sBt[HID_C][IN_C + 8];
    int tid = threadIdx.x;
    float4* sB4 = (float4*)&sBt[0][0];
    for (int i = tid; i < 1088; i += 256) sB4[i] = wtrI[i];   // flat copy, conflict-free
    int row0 = blockIdx.x * ROWS;
    const float4* x4 = (const float4*)x;
    for (int i = tid; i < ROWS * 32; i += 256) {
        int r = i >> 5, q = i & 31;
        float4 f = x4[(size_t)(row0 + r) * 32 + q];
        __half2 ha = __floats2half2_rn(f.x, f.y), hb = __floats2half2_rn(f.z, f.w);
        uint2 u; u.x = *(unsigned*)&ha; u.y = *(unsigned*)&hb;
        *(uint2*)&sA[r][q * 4] = u;
    }
    __syncthreads();
    int lane = tid & 63, wave = tid >> 6;
    f32x4 acc[2];
    mfma_tile<IN_C>(&sA[0][0], &sBt[0][0], lane, wave, acc);
    int m = lane & 15, rg = lane >> 4;
    int r0 = (wave >> 1) * 16, wc = wave & 1;
    #pragma unroll
    for (int nt = 0; nt < 2; ++nt) {
        int col = wc * 32 + nt * 16 + m;
        #pragma unroll
        for (int i = 0; i < 4; ++i) {
            int row = row0 + r0 + rg * 4 + i;
            h[(size_t)row * HID_C + col] = __float2half(acc[nt][i]);
        }
    }
}

// ---------------- fused: gather-mean (fp16 accum) + MFMA combine + ReLU [+ out GEMM] ----------------
template<bool FINAL>
__global__ __launch_bounds__(256) void fused_layer(const __half* __restrict__ h,
                                                   const int2* __restrict__ rc,
                                                   const int* __restrict__ csr,
                                                   const float4* __restrict__ wtrL,
                                                   const float* __restrict__ bias,
                                                   __half* __restrict__ hout,
                                                   const float4* __restrict__ wtrO,
                                                   float* __restrict__ out) {
    __shared__ _Float16 sA[ROWS][136];     // gather: [row][k]: k<64 agg, k>=64 self
    __shared__ _Float16 sBt[HID_C][136];   // [col][k]: k<64 Wa, k>=64 Ws
    int tid = threadIdx.x;
    float4* sB4 = (float4*)&sBt[0][0];
    for (int i = tid; i < 1088; i += 256) sB4[i] = wtrL[i];   // flat copy, conflict-free
    int row0 = blockIdx.x * ROWS;
    int wave = tid >> 6, lane = tid & 63;
    int g4 = lane >> 4;       // edge slot 0..3
    int c16 = lane & 15;      // channels [4*c16, 4*c16+4)
    const uint2* h2u = (const uint2*)h;
    const __half2 hzero = __floats2half2_rn(0.f, 0.f);
    for (int i = 0; i < 8; ++i) {
        int rl = wave * 8 + i;
        int row = row0 + rl;
        int2 rcv = rc[row];
        int start = __builtin_amdgcn_readfirstlane(rcv.x);
        int d     = __builtin_amdgcn_readfirstlane(rcv.y);
        uint2 selfv = h2u[(size_t)row * 16 + c16];
        __half2 p01 = hzero, p23 = hzero;     // fp16 row accumulators
        int j = 0;
        for (; j + 16 <= d; j += 16) {
            uint2 v[4];
            #pragma unroll
            for (int s = 0; s < 4; ++s) {
                int src = csr[start + j + s * 4 + g4];
                v[s] = h2u[(size_t)src * 16 + c16];
            }
            #pragma unroll
            for (int s = 0; s < 4; ++s) {
                p01 += *(__half2*)&v[s].x;
                p23 += *(__half2*)&v[s].y;
            }
        }
        if (j < d) {
            int dm1 = d - 1;
            #pragma unroll
            for (int s = 0; s < 4; ++s) {
                int e = j + s * 4 + g4;
                bool ok = e < d;
                int src = csr[start + min(e, dm1)];
                uint2 vv = h2u[(size_t)src * 16 + c16];
                unsigned vx = ok ? vv.x : 0u, vy = ok ? vv.y : 0u;
                p01 += *(__half2*)&vx;
                p23 += *(__half2*)&vy;
            }
        }
        // cross-slot reduce in packed fp16
        unsigned u01 = *(unsigned*)&p01, u23 = *(unsigned*)&p23;
        unsigned o01 = (unsigned)__shfl_xor((int)u01, 16), o23 = (unsigned)__shfl_xor((int)u23, 16);
        p01 += *(__half2*)&o01; p23 += *(__half2*)&o23;
        u01 = *(unsigned*)&p01; u23 = *(unsigned*)&p23;
        o01 = (unsigned)__shfl_xor((int)u01, 32); o23 = (unsigned)__shfl_xor((int)u23, 32);
        p01 += *(__half2*)&o01; p23 += *(__half2*)&o23;
        if (lane < 16) {
            __half2 hinv = __float2half2_rn(1.f / fmaxf((float)d, 1.f));
            p01 *= hinv; p23 *= hinv;
            uint2 agg2; agg2.x = *(unsigned*)&p01; agg2.y = *(unsigned*)&p23;
            *(uint2*)&sA[rl][4 * c16]      = agg2;    // agg  -> k [0,64)
            *(uint2*)&sA[rl][64 + 4 * c16] = selfv;   // self -> k [64,128)
        }
    }
    __syncthreads();
    f32x4 acc[2];
    mfma_tile<128>(&sA[0][0], &sBt[0][0], lane, wave, acc);
    int m = lane & 15, rg = lane >> 4;
    int r0 = (wave >> 1) * 16, wc = wave & 1;
    if (!FINAL) {
        #pragma unroll
        for (int nt = 0; nt < 2; ++nt) {
            int col = wc * 32 + nt * 16 + m;
            float bv = bias[col];
            #pragma unroll
            for (int i = 0; i < 4; ++i) {
                int row = row0 + r0 + rg * 4 + i;
                hout[(size_t)row * HID_C + col] = __float2half(fmaxf(acc[nt][i] + bv, 0.f));
            }
        }
    } else {
        __syncthreads();     // all MFMA1 LDS reads complete
        // write h2 = relu(acc + b) into sA with LDA=72; stage W_out into sBt
        _Float16* sA72 = &sA[0][0];
        #pragma unroll
        for (int nt = 0; nt < 2; ++nt) {
            int col = wc * 32 + nt * 16 + m;
            float bv = bias[col];
            #pragma unroll
            for (int i = 0; i < 4; ++i) {
                int rl = r0 + rg * 4 + i;
                sA72[rl * 72 + col] = (_Float16)fmaxf(acc[nt][i] + bv, 0.f);
            }
        }
        for (int i = tid; i < 576; i += 256) sB4[i] = wtrO[i];
        __syncthreads();
        f32x4 acc2[2];
        mfma_tile<64>(&sA[0][0], &sBt[0][0], lane, wave, acc2);
        #pragma unroll
        for (int nt = 0; nt < 2; ++nt) {
            int col = wc * 32 + nt * 16 + m;
            #pragma unroll
            for (int i = 0; i < 4; ++i) {
                int row = row0 + r0 + rg * 4 + i;
                out[(size_t)row * OUT_C + col] = acc2[nt][i];
            }
        }
    }
}

extern "C" void kernel_launch(void* const* d_in, const int* in_sizes, int n_in,
                              void* d_out, int out_size, void* d_ws, size_t ws_size,
                              hipStream_t stream) {
    const float* x      = (const float*)d_in[0];
    const int*   ei     = (const int*)  d_in[1];
    const float* W_init = (const float*)d_in[2];
    const float* W_self = (const float*)d_in[3];
    const float* W_agg  = (const float*)d_in[4];
    const float* b      = (const float*)d_in[5];
    const float* W_out  = (const float*)d_in[6];
    float* out = (float*)d_out;

    char* ws = (char*)d_ws;
    const size_t KB = 1 << 10;
    int*      bucket_cursor = (int*)(ws + 0);                 // 1.6 KB
    int*      bucket_base   = (int*)(ws + 2 * KB);            // 1.6 KB
    int2*     rc            = (int2*)(ws + 4 * KB);           // 800 KB
    int*      csr           = (int*)(ws + 1024 * KB);         // 6.4 MB
    _Float16* wtr           = (_Float16*)(ws + 7424 * KB);    // 60 KB
    unsigned* gbuck         = (unsigned*)(ws + 8192 * KB);    // 7.82 MB
    __half*   hA            = (__half*)(ws + 18432 * KB);     // 12.8 MB
    __half*   hB            = (__half*)(ws + 32768 * KB);     // 12.8 MB

    const float4* wtrI  = (const float4*)(wtr);
    const float4* wtrL0 = (const float4*)(wtr + 8704);
    const float4* wtrL1 = (const float4*)(wtr + 17408);
    const float4* wtrO  = (const float4*)(wtr + 26112);

    // weight pre-transpose (independent of graph build)
    transpose_weights<<<112, 256, 0, stream>>>(W_init, W_self, W_agg, W_out, wtr);

    // CSR build: bin -> scan -> build
    hipMemsetAsync(bucket_cursor, 0, NBUCK * sizeof(int), stream);
    bin_kernel<<<(E_EDGES + CHUNK - 1) / CHUNK, 256, 0, stream>>>(ei, bucket_cursor, gbuck);
    scan_buckets<<<1, 512, 0, stream>>>(bucket_cursor, bucket_base);
    build_bucket<<<NBUCK, 256, 0, stream>>>(gbuck, bucket_cursor, bucket_base, csr, rc);

    const int GB = N_NODES / ROWS;   // 3125 (exact)

    init_gemm<<<GB, 256, 0, stream>>>(x, wtrI, hA);

    fused_layer<false><<<GB, 256, 0, stream>>>(hA, rc, csr, wtrL0, b + 0 * HID_C, hB,
                                               wtrO, out);
    fused_layer<true><<<GB, 256, 0, stream>>>(hB, rc, csr, wtrL1, b + 1 * HID_C, hA,
                                              wtrO, out);
}

// Round 8
// 144.041 us; speedup vs baseline: 7.9185x; 1.1692x over previous
//
#include <hip/hip_runtime.h>
#include <hip/hip_fp16.h>

#define N_NODES 100000
#define E_EDGES 1600000
#define IN_C    128
#define HID_C   64
#define OUT_C   64
#define ROWS    32
#define NBUCK   391         // ceil(100000/256) node buckets
#define BSHIFT  8
#define BNODES  256
#define CAP     5120        // bucket capacity (mean 4096, +16 sigma)
#define CHUNK   4096
#define NB_BINCH 391        // ceil(E/CHUNK) bin chunks
#define NB_TR   112
#define IDXCAP  1632
#define IDXMAX  1568

typedef _Float16 f16x8 __attribute__((ext_vector_type(8)));
typedef float    f32x4 __attribute__((ext_vector_type(4)));
#define MFMA16(a, b, c) __builtin_amdgcn_mfma_f32_16x16x32_f16(a, b, c, 0, 0, 0)

// =============== K1: edge binning (blocks 0..390) + weight transpose (391..502) ===============
struct BinS {
    int hist[NBUCK]; int resbase[NBUCK]; int cur[NBUCK];
    unsigned pk[CHUNK]; unsigned short bk[CHUNK];
};

__global__ __launch_bounds__(256) void k1_bin_tr(const int* __restrict__ ei,
                                                 int* __restrict__ bucket_cursor,
                                                 unsigned* __restrict__ gbuck,
                                                 const float* __restrict__ Wi,
                                                 const float* __restrict__ Wsf,
                                                 const float* __restrict__ Waf,
                                                 const float* __restrict__ Wo,
                                                 _Float16* __restrict__ wtr) {
    __shared__ BinS S;
    int tid = threadIdx.x;
    if (blockIdx.x < NB_BINCH) {
        for (int i = tid; i < NBUCK; i += 256) S.hist[i] = 0;
        __syncthreads();
        int base = blockIdx.x * CHUNK;
        for (int i = tid; i < CHUNK; i += 256) {
            int e = base + i;
            if (e < E_EDGES) {
                int dst = ei[e];
                int src = ei[E_EDGES + e];
                int b = dst >> BSHIFT;
                S.pk[i] = ((unsigned)(dst & (BNODES - 1)) << 17) | (unsigned)src;
                S.bk[i] = (unsigned short)b;
                atomicAdd(&S.hist[b], 1);
            } else S.bk[i] = 0xFFFF;
        }
        __syncthreads();
        for (int i = tid; i < NBUCK; i += 256) {
            S.resbase[i] = atomicAdd(&bucket_cursor[i], S.hist[i]);
            S.cur[i] = 0;
        }
        __syncthreads();
        for (int i = tid; i < CHUNK; i += 256) {
            if (S.bk[i] != 0xFFFF) {
                int b = S.bk[i];
                int slot = S.resbase[b] + atomicAdd(&S.cur[b], 1);
                if (slot < CAP) gbuck[(size_t)b * CAP + slot] = S.pk[i];
            }
        }
    } else {
        // weight transpose: [0,8704) init 64x136 | [8704,17408) L0 | [17408,26112) L1 | [26112,30720) out 64x72
        int t = (blockIdx.x - NB_BINCH) * 256 + tid;
        if (t < 8192) {
            int k = t >> 6, col = t & 63;
            wtr[col * 136 + k] = (_Float16)Wi[t];
        } else if (t < 24576) {
            int u = t - 8192; int l = u >> 13; int v = u & 8191;
            int k = v >> 6, col = v & 63;
            float w = (k < 64) ? Waf[l * 4096 + k * 64 + col] : Wsf[l * 4096 + (k - 64) * 64 + col];
            wtr[8704 + l * 8704 + col * 136 + k] = (_Float16)w;
        } else if (t < 28672) {
            int u = t - 24576; int k = u >> 6, col = u & 63;
            wtr[26112 + col * 72 + k] = (_Float16)Wo[u];
        }
    }
}

// =============== K2: bucket CSR build (blocks 0..390) + init GEMM (391..3515) ===============
struct InitS { _Float16 sA[ROWS][IN_C + 8]; _Float16 sBt[HID_C][IN_C + 8]; };
struct BuildS { int lcnt[BNODES]; int lpos[BNODES]; int lcur[BNODES]; int s[2][512]; };
union K2S { InitS ini; BuildS bld; };

// MFMA tile: each of 4 waves computes 16x32 of the 32x64 block output. LDA = K+8.
template<int K>
__device__ __forceinline__ void mfma_tile(const _Float16* sA, const _Float16* sBt,
                                          int lane, int wave, f32x4 acc[2]) {
    const int LDA = K + 8;
    int r0 = (wave >> 1) * 16;
    int wc = wave & 1;
    int m = lane & 15, kg = lane >> 4;
    acc[0] = (f32x4){0.f, 0.f, 0.f, 0.f};
    acc[1] = (f32x4){0.f, 0.f, 0.f, 0.f};
    #pragma unroll
    for (int ks = 0; ks < K / 32; ++ks) {
        f16x8 a = *(const f16x8*)&sA[(r0 + m) * LDA + 32 * ks + 8 * kg];
        #pragma unroll
        for (int nt = 0; nt < 2; ++nt) {
            f16x8 b = *(const f16x8*)&sBt[(wc * 32 + nt * 16 + m) * LDA + 32 * ks + 8 * kg];
            acc[nt] = MFMA16(a, b, acc[nt]);
        }
    }
}

__global__ __launch_bounds__(256) void k2_build_init(const unsigned* __restrict__ gbuck,
                                                     const int* __restrict__ bucket_cursor,
                                                     int* __restrict__ csr,
                                                     int2* __restrict__ rc,
                                                     const float* __restrict__ x,
                                                     const float4* __restrict__ wtrI,
                                                     __half* __restrict__ h) {
    __shared__ K2S U;
    int t = threadIdx.x;
    if (blockIdx.x < NBUCK) {
        BuildS& S = U.bld;
        int b = blockIdx.x;
        int v0 = (t < NBUCK) ? min(bucket_cursor[t], CAP) : 0;
        int v1 = (t + 256 < NBUCK) ? min(bucket_cursor[t + 256], CAP) : 0;
        S.s[0][t] = v0; S.s[0][t + 256] = v1;
        S.lcnt[t] = 0; S.lcur[t] = 0;
        __syncthreads();
        int p = 0;
        for (int off = 1; off < 512; off <<= 1) {     // 9 rounds, inclusive scan of 512
            int a0 = S.s[p][t]       + ((t >= off)       ? S.s[p][t - off] : 0);
            int a1 = S.s[p][t + 256] + ((t + 256 >= off) ? S.s[p][t + 256 - off] : 0);
            S.s[p ^ 1][t] = a0; S.s[p ^ 1][t + 256] = a1;
            __syncthreads();
            p ^= 1;
        }
        int bb = (b == 0) ? 0 : S.s[p][b - 1];        // exclusive base for this bucket
        int ec = min(bucket_cursor[b], CAP);
        int gnode = b * BNODES;
        int nn = min(BNODES, N_NODES - gnode);
        const unsigned* mybuck = gbuck + (size_t)b * CAP;
        __syncthreads();
        for (int i = t; i < ec; i += 256) atomicAdd(&S.lcnt[mybuck[i] >> 17], 1);
        __syncthreads();
        int c = S.lcnt[t];
        S.s[0][t] = c;
        __syncthreads();
        int q = 0;
        for (int off = 1; off < 256; off <<= 1) {     // 8 rounds, inclusive scan of 256
            int a0 = S.s[q][t] + ((t >= off) ? S.s[q][t - off] : 0);
            S.s[q ^ 1][t] = a0;
            __syncthreads();
            q ^= 1;
        }
        int ex = S.s[q][t] - c;
        S.lpos[t] = ex;
        if (t < nn) rc[gnode + t] = make_int2(bb + ex, c);
        __syncthreads();
        for (int i = t; i < ec; i += 256) {
            unsigned pkt = mybuck[i];
            int dl = pkt >> 17;
            int slot = S.lpos[dl] + atomicAdd(&S.lcur[dl], 1);
            csr[bb + slot] = (int)(pkt & 0x1FFFF);
        }
    } else {
        InitS& S = U.ini;
        int row0 = (blockIdx.x - NBUCK) * ROWS;
        float4* sB4 = (float4*)&S.sBt[0][0];
        for (int i = t; i < 1088; i += 256) sB4[i] = wtrI[i];
        const float4* x4 = (const float4*)x;
        for (int i = t; i < ROWS * 32; i += 256) {
            int r = i >> 5, qq = i & 31;
            float4 f = x4[(size_t)(row0 + r) * 32 + qq];
            __half2 ha = __floats2half2_rn(f.x, f.y), hb = __floats2half2_rn(f.z, f.w);
            uint2 u; u.x = *(unsigned*)&ha; u.y = *(unsigned*)&hb;
            *(uint2*)&S.sA[r][qq * 4] = u;
        }
        __syncthreads();
        int lane = t & 63, wave = t >> 6;
        f32x4 acc[2];
        mfma_tile<IN_C>(&S.sA[0][0], &S.sBt[0][0], lane, wave, acc);
        int m = lane & 15, rg = lane >> 4;
        int r0 = (wave >> 1) * 16, wc = wave & 1;
        #pragma unroll
        for (int nt = 0; nt < 2; ++nt) {
            int col = wc * 32 + nt * 16 + m;
            #pragma unroll
            for (int i = 0; i < 4; ++i) {
                int row = row0 + r0 + rg * 4 + i;
                h[(size_t)row * HID_C + col] = __float2half(acc[nt][i]);
            }
        }
    }
}

// =============== fused: LDS-staged-idx gather + MFMA combine + ReLU [+ out GEMM] ===============
#define GCHUNK(r, JB, CLAMP)                                                    \
    {                                                                           \
        _Pragma("unroll")                                                       \
        for (int s = 0; s < 4; ++s) {                                           \
            int ee = (JB) + s * 4 + g4;                                         \
            int a = sl[r] + ee;                                                 \
            if (CLAMP) a = min(a, IDXCAP - 1);                                  \
            int src = sIdx[a];                                                  \
            uint2 vv = h2u[(size_t)src * 16 + c16];                             \
            bool ok = ee < dd[r];                                               \
            unsigned vx = ok ? vv.x : 0u, vy = ok ? vv.y : 0u;                  \
            p01[r] += *(__half2*)&vx;                                           \
            p23[r] += *(__half2*)&vy;                                           \
        }                                                                       \
    }

template<bool FINAL>
__global__ __launch_bounds__(256) void fused_layer(const __half* __restrict__ h,
                                                   const int2* __restrict__ rc,
                                                   const int* __restrict__ csr,
                                                   const float4* __restrict__ wtrL,
                                                   const float* __restrict__ bias,
                                                   __half* __restrict__ hout,
                                                   const float4* __restrict__ wtrO,
                                                   float* __restrict__ out) {
    __shared__ _Float16 sA[ROWS][136];     // [row][k]: k<64 agg, k>=64 self
    __shared__ _Float16 sBt[HID_C][136];   // [col][k]: k<64 Wa, k>=64 Ws
    __shared__ int sIdx[IDXCAP];           // block's contiguous csr span
    __shared__ int2 sRC[ROWS];
    int tid = threadIdx.x;
    float4* sB4 = (float4*)&sBt[0][0];
    for (int i = tid; i < 1088; i += 256) sB4[i] = wtrL[i];
    int row0 = blockIdx.x * ROWS;
    const uint2* h2u = (const uint2*)h;

    if (tid < 32) sRC[tid] = rc[row0 + tid];
    int2 rcF = rc[row0];
    int2 rcL = rc[row0 + 31];
    int e0 = __builtin_amdgcn_readfirstlane(rcF.x);
    int e1 = __builtin_amdgcn_readfirstlane(rcL.x) + __builtin_amdgcn_readfirstlane(rcL.y);
    int Lc = min(e1 - e0, IDXMAX);
    for (int i = tid; i < Lc; i += 256) sIdx[i] = csr[e0 + i];
    if (tid < 64) sIdx[min(Lc + tid, IDXCAP - 1)] = 0;      // pad
    // stage self rows (contiguous) into sA[.][64..128)
    for (int i = tid; i < 512; i += 256) {
        int r = i >> 4, qq = i & 15;
        *(uint2*)&sA[r][64 + qq * 4] = h2u[(size_t)(row0 + r) * 16 + qq];
    }
    __syncthreads();

    int wave = tid >> 6, lane = tid & 63;
    int g4 = lane >> 4;       // edge slot 0..3
    int c16 = lane & 15;      // channels [4*c16, 4*c16+4)
    int sl[8], dd[8];
    #pragma unroll
    for (int r = 0; r < 8; ++r) {
        int2 v = sRC[wave * 8 + r];
        sl[r] = min(__builtin_amdgcn_readfirstlane(v.x) - e0, IDXMAX);
        dd[r] = __builtin_amdgcn_readfirstlane(v.y);
    }
    const __half2 hzero = __floats2half2_rn(0.f, 0.f);
    __half2 p01[8], p23[8];
    #pragma unroll
    for (int r = 0; r < 8; ++r) { p01[r] = hzero; p23[r] = hzero; }

    // chunks 0 and 1 for all 8 rows: one straight-line block, ~64 loads in flight
    #pragma unroll
    for (int r = 0; r < 8; ++r) GCHUNK(r, 0, false)
    #pragma unroll
    for (int r = 0; r < 8; ++r) GCHUNK(r, 16, false)
    // rare long tail
    int dmax = dd[0];
    #pragma unroll
    for (int r = 1; r < 8; ++r) dmax = max(dmax, dd[r]);
    if (dmax > 32) {
        #pragma unroll
        for (int r = 0; r < 8; ++r)
            for (int j = 32; j < dd[r]; j += 16) GCHUNK(r, j, true)
    }

    // cross-slot reduce (packed fp16) + mean + write agg
    #pragma unroll
    for (int r = 0; r < 8; ++r) {
        unsigned u01 = *(unsigned*)&p01[r], u23 = *(unsigned*)&p23[r];
        unsigned o01 = (unsigned)__shfl_xor((int)u01, 16);
        unsigned o23 = (unsigned)__shfl_xor((int)u23, 16);
        p01[r] += *(__half2*)&o01; p23[r] += *(__half2*)&o23;
        u01 = *(unsigned*)&p01[r]; u23 = *(unsigned*)&p23[r];
        o01 = (unsigned)__shfl_xor((int)u01, 32);
        o23 = (unsigned)__shfl_xor((int)u23, 32);
        p01[r] += *(__half2*)&o01; p23[r] += *(__half2*)&o23;
        if (lane < 16) {
            __half2 hinv = __float2half2_rn(1.f / fmaxf((float)dd[r], 1.f));
            __half2 q01 = p01[r] * hinv, q23 = p23[r] * hinv;
            uint2 agg2; agg2.x = *(unsigned*)&q01; agg2.y = *(unsigned*)&q23;
            *(uint2*)&sA[wave * 8 + r][4 * c16] = agg2;
        }
    }
    __syncthreads();

    f32x4 acc[2];
    mfma_tile<128>(&sA[0][0], &sBt[0][0], lane, wave, acc);
    int m = lane & 15, rg = lane >> 4;
    int r0 = (wave >> 1) * 16, wc = wave & 1;
    if (!FINAL) {
        #pragma unroll
        for (int nt = 0; nt < 2; ++nt) {
            int col = wc * 32 + nt * 16 + m;
            float bv = bias[col];
            #pragma unroll
            for (int i = 0; i < 4; ++i) {
                int row = row0 + r0 + rg * 4 + i;
                hout[(size_t)row * HID_C + col] = __float2half(fmaxf(acc[nt][i] + bv, 0.f));
            }
        }
    } else {
        __syncthreads();
        _Float16* sA72 = &sA[0][0];
        #pragma unroll
        for (int nt = 0; nt < 2; ++nt) {
            int col = wc * 32 + nt * 16 + m;
            float bv = bias[col];
            #pragma unroll
            for (int i = 0; i < 4; ++i) {
                int rl = r0 + rg * 4 + i;
                sA72[rl * 72 + col] = (_Float16)fmaxf(acc[nt][i] + bv, 0.f);
            }
        }
        for (int i = tid; i < 576; i += 256) sB4[i] = wtrO[i];
        __syncthreads();
        f32x4 acc2[2];
        mfma_tile<64>(&sA[0][0], &sBt[0][0], lane, wave, acc2);
        #pragma unroll
        for (int nt = 0; nt < 2; ++nt) {
            int col = wc * 32 + nt * 16 + m;
            #pragma unroll
            for (int i = 0; i < 4; ++i) {
                int row = row0 + r0 + rg * 4 + i;
                out[(size_t)row * OUT_C + col] = acc2[nt][i];
            }
        }
    }
}

extern "C" void kernel_launch(void* const* d_in, const int* in_sizes, int n_in,
                              void* d_out, int out_size, void* d_ws, size_t ws_size,
                              hipStream_t stream) {
    const float* x      = (const float*)d_in[0];
    const int*   ei     = (const int*)  d_in[1];
    const float* W_init = (const float*)d_in[2];
    const float* W_self = (const float*)d_in[3];
    const float* W_agg  = (const float*)d_in[4];
    const float* b      = (const float*)d_in[5];
    const float* W_out  = (const float*)d_in[6];
    float* out = (float*)d_out;

    char* ws = (char*)d_ws;
    const size_t KB = 1 << 10;
    int*      bucket_cursor = (int*)(ws + 0);                 // 1.6 KB
    int2*     rc            = (int2*)(ws + 4 * KB);           // 800 KB
    int*      csr           = (int*)(ws + 1024 * KB);         // 6.4 MB
    _Float16* wtr           = (_Float16*)(ws + 7424 * KB);    // 60 KB
    unsigned* gbuck         = (unsigned*)(ws + 8192 * KB);    // 7.82 MB
    __half*   hA            = (__half*)(ws + 18432 * KB);     // 12.8 MB
    __half*   hB            = (__half*)(ws + 32768 * KB);     // 12.8 MB

    const float4* wtrI  = (const float4*)(wtr);
    const float4* wtrL0 = (const float4*)(wtr + 8704);
    const float4* wtrL1 = (const float4*)(wtr + 17408);
    const float4* wtrO  = (const float4*)(wtr + 26112);

    hipMemsetAsync(bucket_cursor, 0, NBUCK * sizeof(int), stream);
    k1_bin_tr<<<NB_BINCH + NB_TR, 256, 0, stream>>>(ei, bucket_cursor, gbuck,
                                                    W_init, W_self, W_agg, W_out, wtr);
    k2_build_init<<<NBUCK + N_NODES / ROWS, 256, 0, stream>>>(gbuck, bucket_cursor, csr, rc,
                                                              x, wtrI, hA);
    const int GB = N_NODES / ROWS;   // 3125
    fused_layer<false><<<GB, 256, 0, stream>>>(hA, rc, csr, wtrL0, b + 0 * HID_C, hB,
                                               wtrO, out);
    fused_layer<true><<<GB, 256, 0, stream>>>(hB, rc, csr, wtrL1, b + 1 * HID_C, hA,
                                              wtrO, out);
}

// Round 9
// 136.913 us; speedup vs baseline: 8.3307x; 1.0521x over previous
//
#include <hip/hip_runtime.h>
#include <hip/hip_fp16.h>

#define N_NODES 100000
#define E_EDGES 1600000
#define IN_C    128
#define HID_C   64
#define OUT_C   64
#define ROWS    32
#define NBUCK   391         // ceil(100000/256) node buckets
#define BSHIFT  8
#define BNODES  256
#define CAP     5120        // bucket capacity (mean 4096, +16 sigma)
#define CHUNK   4096
#define NB_BINCH 391        // ceil(E/CHUNK) bin chunks
#define NB_TR   112
#define IDXCAP  1632
#define IDXMAX  1568

typedef _Float16 f16x8 __attribute__((ext_vector_type(8)));
typedef float    f32x4 __attribute__((ext_vector_type(4)));
#define MFMA16(a, b, c) __builtin_amdgcn_mfma_f32_16x16x32_f16(a, b, c, 0, 0, 0)

// =============== K1: edge binning (blocks 0..390) + weight transpose (391..502) ===============
struct BinS {
    int hist[NBUCK]; int resbase[NBUCK]; int cur[NBUCK];
    unsigned pk[CHUNK]; unsigned short bk[CHUNK];
};

__global__ __launch_bounds__(256) void k1_bin_tr(const int* __restrict__ ei,
                                                 int* __restrict__ bucket_cursor,
                                                 unsigned* __restrict__ gbuck,
                                                 const float* __restrict__ Wi,
                                                 const float* __restrict__ Wsf,
                                                 const float* __restrict__ Waf,
                                                 const float* __restrict__ Wo,
                                                 _Float16* __restrict__ wtr) {
    __shared__ BinS S;
    int tid = threadIdx.x;
    if (blockIdx.x < NB_BINCH) {
        for (int i = tid; i < NBUCK; i += 256) S.hist[i] = 0;
        __syncthreads();
        int base = blockIdx.x * CHUNK;
        for (int i = tid; i < CHUNK; i += 256) {
            int e = base + i;
            if (e < E_EDGES) {
                int dst = ei[e];
                int src = ei[E_EDGES + e];
                int b = dst >> BSHIFT;
                S.pk[i] = ((unsigned)(dst & (BNODES - 1)) << 17) | (unsigned)src;
                S.bk[i] = (unsigned short)b;
                atomicAdd(&S.hist[b], 1);
            } else S.bk[i] = 0xFFFF;
        }
        __syncthreads();
        for (int i = tid; i < NBUCK; i += 256) {
            S.resbase[i] = atomicAdd(&bucket_cursor[i], S.hist[i]);
            S.cur[i] = 0;
        }
        __syncthreads();
        for (int i = tid; i < CHUNK; i += 256) {
            if (S.bk[i] != 0xFFFF) {
                int b = S.bk[i];
                int slot = S.resbase[b] + atomicAdd(&S.cur[b], 1);
                if (slot < CAP) gbuck[(size_t)b * CAP + slot] = S.pk[i];
            }
        }
    } else {
        // weight transpose: [0,8704) init 64x136 | [8704,17408) L0 | [17408,26112) L1 | [26112,30720) out 64x72
        int t = (blockIdx.x - NB_BINCH) * 256 + tid;
        if (t < 8192) {
            int k = t >> 6, col = t & 63;
            wtr[col * 136 + k] = (_Float16)Wi[t];
        } else if (t < 24576) {
            int u = t - 8192; int l = u >> 13; int v = u & 8191;
            int k = v >> 6, col = v & 63;
            float w = (k < 64) ? Waf[l * 4096 + k * 64 + col] : Wsf[l * 4096 + (k - 64) * 64 + col];
            wtr[8704 + l * 8704 + col * 136 + k] = (_Float16)w;
        } else if (t < 28672) {
            int u = t - 24576; int k = u >> 6, col = u & 63;
            wtr[26112 + col * 72 + k] = (_Float16)Wo[u];
        }
    }
}

// =============== K2: bucket CSR build (blocks 0..390) + init GEMM (391..3515) ===============
struct InitS { _Float16 sA[ROWS][IN_C + 8]; _Float16 sBt[HID_C][IN_C + 8]; };
struct BuildS { int lcnt[BNODES]; int lpos[BNODES]; int lcur[BNODES]; int s[2][512]; };
union K2S { InitS ini; BuildS bld; };

// MFMA tile with LDS-staged B: each of 4 waves computes 16x32 of 32x64. LDA = K+8.
template<int K>
__device__ __forceinline__ void mfma_tile(const _Float16* sA, const _Float16* sBt,
                                          int lane, int wave, f32x4 acc[2]) {
    const int LDA = K + 8;
    int r0 = (wave >> 1) * 16;
    int wc = wave & 1;
    int m = lane & 15, kg = lane >> 4;
    acc[0] = (f32x4){0.f, 0.f, 0.f, 0.f};
    acc[1] = (f32x4){0.f, 0.f, 0.f, 0.f};
    #pragma unroll
    for (int ks = 0; ks < K / 32; ++ks) {
        f16x8 a = *(const f16x8*)&sA[(r0 + m) * LDA + 32 * ks + 8 * kg];
        #pragma unroll
        for (int nt = 0; nt < 2; ++nt) {
            f16x8 b = *(const f16x8*)&sBt[(wc * 32 + nt * 16 + m) * LDA + 32 * ks + 8 * kg];
            acc[nt] = MFMA16(a, b, acc[nt]);
        }
    }
}

// MFMA tile with register-resident B fragments
template<int NKS>
__device__ __forceinline__ void mfma_regB(const _Float16* aBase, int lda, int m,
                                          int kg, const f16x8* bf0, const f16x8* bf1,
                                          f32x4 acc[2]) {
    #pragma unroll
    for (int ks = 0; ks < NKS; ++ks) {
        f16x8 a = *(const f16x8*)&aBase[m * lda + 32 * ks + 8 * kg];
        acc[0] = MFMA16(a, bf0[ks], acc[0]);
        acc[1] = MFMA16(a, bf1[ks], acc[1]);
    }
}

__global__ __launch_bounds__(256) void k2_build_init(const unsigned* __restrict__ gbuck,
                                                     const int* __restrict__ bucket_cursor,
                                                     int* __restrict__ csr,
                                                     int2* __restrict__ rc,
                                                     const float* __restrict__ x,
                                                     const float4* __restrict__ wtrI,
                                                     __half* __restrict__ h) {
    __shared__ K2S U;
    int t = threadIdx.x;
    if (blockIdx.x < NBUCK) {
        BuildS& S = U.bld;
        int b = blockIdx.x;
        int v0 = (t < NBUCK) ? min(bucket_cursor[t], CAP) : 0;
        int v1 = (t + 256 < NBUCK) ? min(bucket_cursor[t + 256], CAP) : 0;
        S.s[0][t] = v0; S.s[0][t + 256] = v1;
        S.lcnt[t] = 0; S.lcur[t] = 0;
        __syncthreads();
        int p = 0;
        for (int off = 1; off < 512; off <<= 1) {
            int a0 = S.s[p][t]       + ((t >= off)       ? S.s[p][t - off] : 0);
            int a1 = S.s[p][t + 256] + ((t + 256 >= off) ? S.s[p][t + 256 - off] : 0);
            S.s[p ^ 1][t] = a0; S.s[p ^ 1][t + 256] = a1;
            __syncthreads();
            p ^= 1;
        }
        int bb = (b == 0) ? 0 : S.s[p][b - 1];
        int ec = min(bucket_cursor[b], CAP);
        int gnode = b * BNODES;
        int nn = min(BNODES, N_NODES - gnode);
        const unsigned* mybuck = gbuck + (size_t)b * CAP;
        __syncthreads();
        for (int i = t; i < ec; i += 256) atomicAdd(&S.lcnt[mybuck[i] >> 17], 1);
        __syncthreads();
        int c = S.lcnt[t];
        S.s[0][t] = c;
        __syncthreads();
        int q = 0;
        for (int off = 1; off < 256; off <<= 1) {
            int a0 = S.s[q][t] + ((t >= off) ? S.s[q][t - off] : 0);
            S.s[q ^ 1][t] = a0;
            __syncthreads();
            q ^= 1;
        }
        int ex = S.s[q][t] - c;
        S.lpos[t] = ex;
        if (t < nn) rc[gnode + t] = make_int2(bb + ex, c);
        __syncthreads();
        for (int i = t; i < ec; i += 256) {
            unsigned pkt = mybuck[i];
            int dl = pkt >> 17;
            int slot = S.lpos[dl] + atomicAdd(&S.lcur[dl], 1);
            csr[bb + slot] = (int)(pkt & 0x1FFFF);
        }
    } else {
        InitS& S = U.ini;
        int row0 = (blockIdx.x - NBUCK) * ROWS;
        float4* sB4 = (float4*)&S.sBt[0][0];
        for (int i = t; i < 1088; i += 256) sB4[i] = wtrI[i];
        const float4* x4 = (const float4*)x;
        for (int i = t; i < ROWS * 32; i += 256) {
            int r = i >> 5, qq = i & 31;
            float4 f = x4[(size_t)(row0 + r) * 32 + qq];
            __half2 ha = __floats2half2_rn(f.x, f.y), hb = __floats2half2_rn(f.z, f.w);
            uint2 u; u.x = *(unsigned*)&ha; u.y = *(unsigned*)&hb;
            *(uint2*)&S.sA[r][qq * 4] = u;
        }
        __syncthreads();
        int lane = t & 63, wave = t >> 6;
        f32x4 acc[2];
        mfma_tile<IN_C>(&S.sA[0][0], &S.sBt[0][0], lane, wave, acc);
        int m = lane & 15, rg = lane >> 4;
        int r0 = (wave >> 1) * 16, wc = wave & 1;
        #pragma unroll
        for (int nt = 0; nt < 2; ++nt) {
            int col = wc * 32 + nt * 16 + m;
            #pragma unroll
            for (int i = 0; i < 4; ++i) {
                int row = row0 + r0 + rg * 4 + i;
                h[(size_t)row * HID_C + col] = __float2half(acc[nt][i]);
            }
        }
    }
}

// =============== fused: adaptive LDS-idx gather + reg-B MFMA + ReLU [+ out GEMM] ===============
template<bool FINAL>
__global__ __launch_bounds__(256, 5) void fused_layer(const __half* __restrict__ h,
                                                      const int2* __restrict__ rc,
                                                      const int* __restrict__ csr,
                                                      const _Float16* __restrict__ wB,
                                                      const float* __restrict__ bias,
                                                      __half* __restrict__ hout,
                                                      const _Float16* __restrict__ wO,
                                                      float* __restrict__ out) {
    __shared__ _Float16 sA[ROWS][136];     // [row][k]: k<64 agg, k>=64 self
    __shared__ int sIdx[IDXCAP];           // block's contiguous csr span
    __shared__ int2 sRC[ROWS];
    int tid = threadIdx.x;
    int wave = tid >> 6, lane = tid & 63;
    int m = lane & 15, kg = lane >> 4, wc = wave & 1;
    int row0 = blockIdx.x * ROWS;
    const uint2* h2u = (const uint2*)h;

    // B fragments -> registers (L2-hot broadcast, issued before gather)
    f16x8 bf0[4], bf1[4];
    #pragma unroll
    for (int ks = 0; ks < 4; ++ks) {
        bf0[ks] = *(const f16x8*)&wB[(wc * 32 + m) * 136 + 32 * ks + 8 * kg];
        bf1[ks] = *(const f16x8*)&wB[(wc * 32 + 16 + m) * 136 + 32 * ks + 8 * kg];
    }

    if (tid < 32) sRC[tid] = rc[row0 + tid];
    int2 rcF = rc[row0];
    int2 rcL = rc[row0 + 31];
    int e0 = __builtin_amdgcn_readfirstlane(rcF.x);
    int e1 = __builtin_amdgcn_readfirstlane(rcL.x) + __builtin_amdgcn_readfirstlane(rcL.y);
    int Lc = min(e1 - e0, IDXMAX);
    for (int i = tid; i < Lc; i += 256) sIdx[i] = csr[e0 + i];
    if (tid < 64) sIdx[min(Lc + tid, IDXCAP - 1)] = 0;      // pad
    // stage self rows (contiguous) into sA[.][64..128)
    for (int i = tid; i < 512; i += 256) {
        int r = i >> 4, qq = i & 15;
        *(uint2*)&sA[r][64 + qq * 4] = h2u[(size_t)(row0 + r) * 16 + qq];
    }
    __syncthreads();

    int g4 = lane >> 4;       // edge slot 0..3
    int c16 = lane & 15;      // channels [4*c16, 4*c16+4)
    int sl[8], dd[8];
    int dmax = 0;
    #pragma unroll
    for (int r = 0; r < 8; ++r) {
        int2 v = sRC[wave * 8 + r];
        sl[r] = min(__builtin_amdgcn_readfirstlane(v.x) - e0, IDXMAX);
        dd[r] = __builtin_amdgcn_readfirstlane(v.y);
        dmax = max(dmax, dd[r]);
    }
    const __half2 hzero = __floats2half2_rn(0.f, 0.f);
    __half2 p01[8], p23[8];
    #pragma unroll
    for (int r = 0; r < 8; ++r) { p01[r] = hzero; p23[r] = hzero; }

    // adaptive gather: 8 edges per row-visit; finished rows skipped by SCALAR branch
    for (int c8 = 0; c8 < dmax; c8 += 8) {
        #pragma unroll
        for (int r = 0; r < 8; ++r) {
            if (c8 < dd[r]) {            // dd is SGPR -> s_cbranch, no divergence
                #pragma unroll
                for (int s = 0; s < 2; ++s) {
                    int ee = c8 + s * 4 + g4;
                    int src = sIdx[sl[r] + ee];
                    uint2 vv = h2u[(size_t)src * 16 + c16];
                    bool ok = ee < dd[r];
                    unsigned vx = ok ? vv.x : 0u, vy = ok ? vv.y : 0u;
                    p01[r] += *(__half2*)&vx;
                    p23[r] += *(__half2*)&vy;
                }
            }
        }
    }

    // cross-slot reduce (packed fp16) + mean + write agg
    #pragma unroll
    for (int r = 0; r < 8; ++r) {
        unsigned u01 = *(unsigned*)&p01[r], u23 = *(unsigned*)&p23[r];
        unsigned o01 = (unsigned)__shfl_xor((int)u01, 16);
        unsigned o23 = (unsigned)__shfl_xor((int)u23, 16);
        p01[r] += *(__half2*)&o01; p23[r] += *(__half2*)&o23;
        u01 = *(unsigned*)&p01[r]; u23 = *(unsigned*)&p23[r];
        o01 = (unsigned)__shfl_xor((int)u01, 32);
        o23 = (unsigned)__shfl_xor((int)u23, 32);
        p01[r] += *(__half2*)&o01; p23[r] += *(__half2*)&o23;
        if (lane < 16) {
            __half2 hinv = __float2half2_rn(1.f / fmaxf((float)dd[r], 1.f));
            __half2 q01 = p01[r] * hinv, q23 = p23[r] * hinv;
            uint2 agg2; agg2.x = *(unsigned*)&q01; agg2.y = *(unsigned*)&q23;
            *(uint2*)&sA[wave * 8 + r][4 * c16] = agg2;
        }
    }
    __syncthreads();

    f32x4 acc[2];
    acc[0] = (f32x4){0.f, 0.f, 0.f, 0.f};
    acc[1] = (f32x4){0.f, 0.f, 0.f, 0.f};
    int r0 = (wave >> 1) * 16;
    mfma_regB<4>(&sA[r0][0], 136, m, kg, bf0, bf1, acc);
    int rg = lane >> 4;
    if (!FINAL) {
        #pragma unroll
        for (int nt = 0; nt < 2; ++nt) {
            int col = wc * 32 + nt * 16 + m;
            float bv = bias[col];
            f32x4 a = (nt == 0) ? acc[0] : acc[1];
            #pragma unroll
            for (int i = 0; i < 4; ++i) {
                int row = row0 + r0 + rg * 4 + i;
                hout[(size_t)row * HID_C + col] = __float2half(fmaxf(a[i] + bv, 0.f));
            }
        }
    } else {
        __syncthreads();     // all MFMA1 LDS reads complete
        _Float16* sA72 = &sA[0][0];
        #pragma unroll
        for (int nt = 0; nt < 2; ++nt) {
            int col = wc * 32 + nt * 16 + m;
            float bv = bias[col];
            f32x4 a = (nt == 0) ? acc[0] : acc[1];
            #pragma unroll
            for (int i = 0; i < 4; ++i) {
                int rl = r0 + rg * 4 + i;
                sA72[rl * 72 + col] = (_Float16)fmaxf(a[i] + bv, 0.f);
            }
        }
        f16x8 of0[2], of1[2];
        #pragma unroll
        for (int ks = 0; ks < 2; ++ks) {
            of0[ks] = *(const f16x8*)&wO[(wc * 32 + m) * 72 + 32 * ks + 8 * kg];
            of1[ks] = *(const f16x8*)&wO[(wc * 32 + 16 + m) * 72 + 32 * ks + 8 * kg];
        }
        __syncthreads();
        f32x4 acc2[2];
        acc2[0] = (f32x4){0.f, 0.f, 0.f, 0.f};
        acc2[1] = (f32x4){0.f, 0.f, 0.f, 0.f};
        mfma_regB<2>(&sA72[r0 * 72], 72, m, kg, of0, of1, acc2);
        #pragma unroll
        for (int nt = 0; nt < 2; ++nt) {
            int col = wc * 32 + nt * 16 + m;
            f32x4 a = (nt == 0) ? acc2[0] : acc2[1];
            #pragma unroll
            for (int i = 0; i < 4; ++i) {
                int row = row0 + r0 + rg * 4 + i;
                out[(size_t)row * OUT_C + col] = a[i];
            }
        }
    }
}

extern "C" void kernel_launch(void* const* d_in, const int* in_sizes, int n_in,
                              void* d_out, int out_size, void* d_ws, size_t ws_size,
                              hipStream_t stream) {
    const float* x      = (const float*)d_in[0];
    const int*   ei     = (const int*)  d_in[1];
    const float* W_init = (const float*)d_in[2];
    const float* W_self = (const float*)d_in[3];
    const float* W_agg  = (const float*)d_in[4];
    const float* b      = (const float*)d_in[5];
    const float* W_out  = (const float*)d_in[6];
    float* out = (float*)d_out;

    char* ws = (char*)d_ws;
    const size_t KB = 1 << 10;
    int*      bucket_cursor = (int*)(ws + 0);                 // 1.6 KB
    int2*     rc            = (int2*)(ws + 4 * KB);           // 800 KB
    int*      csr           = (int*)(ws + 1024 * KB);         // 6.4 MB
    _Float16* wtr           = (_Float16*)(ws + 7424 * KB);    // 60 KB
    unsigned* gbuck         = (unsigned*)(ws + 8192 * KB);    // 7.82 MB
    __half*   hA            = (__half*)(ws + 18432 * KB);     // 12.8 MB
    __half*   hB            = (__half*)(ws + 32768 * KB);     // 12.8 MB

    const float4*   wtrI  = (const float4*)(wtr);
    const _Float16* wtrL0 = wtr + 8704;
    const _Float16* wtrL1 = wtr + 17408;
    const _Float16* wtrO  = wtr + 26112;

    hipMemsetAsync(bucket_cursor, 0, NBUCK * sizeof(int), stream);
    k1_bin_tr<<<NB_BINCH + NB_TR, 256, 0, stream>>>(ei, bucket_cursor, gbuck,
                                                    W_init, W_self, W_agg, W_out, wtr);
    k2_build_init<<<NBUCK + N_NODES / ROWS, 256, 0, stream>>>(gbuck, bucket_cursor, csr, rc,
                                                              x, wtrI, hA);
    const int GB = N_NODES / ROWS;   // 3125
    fused_layer<false><<<GB, 256, 0, stream>>>(hA, rc, csr, wtrL0, b + 0 * HID_C, hB,
                                               wtrO, out);
    fused_layer<true><<<GB, 256, 0, stream>>>(hB, rc, csr, wtrL1, b + 1 * HID_C, hA,
                                              wtrO, out);
}